// Round 1
// baseline (1324.260 us; speedup 1.0000x reference)
//
#include <hip/hip_runtime.h>
#include <hip/hip_fp16.h>
#include <cstdint>
#include <cstddef>

typedef _Float16 f16;
typedef _Float16 f16x8 __attribute__((ext_vector_type(8)));
typedef _Float16 f16x4 __attribute__((ext_vector_type(4)));
typedef float f32x4 __attribute__((ext_vector_type(4)));

#define NB 64
#define SEQ 512
#define HDIM 1024
#define NHEAD 8
#define HD 128
#define MR (NB * SEQ)      // 32768 rows
#define QKV_LD 3072

// async 16B/lane global->LDS. LDS dest = wave-uniform base + lane*16.
__device__ __forceinline__ void async_copy16(const f16* g, f16* l) {
  __builtin_amdgcn_global_load_lds(
      (__attribute__((address_space(1))) void*)(void*)const_cast<f16*>(g),
      (__attribute__((address_space(3))) void*)l, 16, 0, 0);
}

// ---------------- small prep kernels ----------------

__global__ __launch_bounds__(256) void conv_reduce(
    const float* __restrict__ cw, const float* __restrict__ cb,
    float* __restrict__ out2) {
  int t = threadIdx.x;
  float a = 0.f, b = 0.f;
  for (int i = t; i < HDIM; i += 256) { a += cw[i]; b += cb[i]; }
  for (int m = 32; m >= 1; m >>= 1) { a += __shfl_xor(a, m); b += __shfl_xor(b, m); }
  __shared__ float sa[4], sb[4];
  if ((t & 63) == 0) { sa[t >> 6] = a; sb[t >> 6] = b; }
  __syncthreads();
  if (t == 0) {
    out2[0] = (sa[0] + sa[1] + sa[2] + sa[3]) * (1.f / HDIM);
    out2[1] = (sb[0] + sb[1] + sb[2] + sb[3]) * (1.f / HDIM);
  }
}

// y = x*(1+mean(conv_w)) + mean(conv_b), cast f16. 4 elems/thread.
__global__ __launch_bounds__(256) void prep_x(
    const float* __restrict__ x, const float* __restrict__ cs,
    f16* __restrict__ xh) {
  size_t i = (size_t)blockIdx.x * 256 + threadIdx.x;
  float cw = 1.f + cs[0], cb = cs[1];
  float4 v = ((const float4*)x)[i];
  f16x4 o;
  o[0] = (f16)(v.x * cw + cb);
  o[1] = (f16)(v.y * cw + cb);
  o[2] = (f16)(v.z * cw + cb);
  o[3] = (f16)(v.w * cw + cb);
  ((f16x4*)xh)[i] = o;
}

__global__ __launch_bounds__(256) void concat_bias(
    const float* __restrict__ bq, const float* __restrict__ bk,
    const float* __restrict__ bv, float* __restrict__ dst) {
  int i = blockIdx.x * 256 + threadIdx.x;  // 3072
  if (i < 1024) dst[i] = bq[i];
  else if (i < 2048) dst[i] = bk[i - 1024];
  else dst[i] = bv[i - 2048];
}

// W [K,N] fp32 -> WT [N,K] f16 (NT-gemm weight layout)
__global__ __launch_bounds__(256) void transpose_cast(
    const float* __restrict__ src, f16* __restrict__ dst, int K, int N) {
  __shared__ float tile[32][33];
  int tx = threadIdx.x, ty = threadIdx.y;
  int n0 = blockIdx.x * 32, k0 = blockIdx.y * 32;
#pragma unroll
  for (int r = 0; r < 32; r += 8) tile[ty + r][tx] = src[(size_t)(k0 + ty + r) * N + n0 + tx];
  __syncthreads();
#pragma unroll
  for (int r = 0; r < 32; r += 8)
    dst[(size_t)(n0 + ty + r) * K + k0 + tx] = (f16)tile[tx][ty + r];
}

// v section of qkv [m, 2048 + h*128 + d] -> vT[(b*8+h)*128 + d][m]
__global__ __launch_bounds__(256) void transpose_v(
    const f16* __restrict__ qkv, f16* __restrict__ vT) {
  __shared__ f16 tile[32][33];
  int tx = threadIdx.x, ty = threadIdx.y;
  int m0 = blockIdx.x * 32, d0 = blockIdx.y * 32;
  int bh = blockIdx.z;
  int bb = bh >> 3, h = bh & 7;
  const f16* src = qkv + (size_t)(bb * SEQ) * QKV_LD + 2048 + h * 128;
#pragma unroll
  for (int r = 0; r < 32; r += 8) tile[ty + r][tx] = src[(size_t)(m0 + ty + r) * QKV_LD + d0 + tx];
  __syncthreads();
  f16* dstp = vT + (size_t)bh * HD * SEQ;
#pragma unroll
  for (int r = 0; r < 32; r += 8)
    dstp[(size_t)(d0 + ty + r) * SEQ + m0 + tx] = tile[tx][ty + r];
}

// LayerNorm over H=1024, fp32 in (x_reg), f16 out (x_norm)
__global__ __launch_bounds__(256) void ln_kernel(
    const float* __restrict__ xin, const float* __restrict__ g,
    const float* __restrict__ bta, f16* __restrict__ out) {
  int row = blockIdx.x;
  int t = threadIdx.x;
  float4 v = ((const float4*)(xin + (size_t)row * HDIM))[t];
  float s = v.x + v.y + v.z + v.w;
  float s2 = v.x * v.x + v.y * v.y + v.z * v.z + v.w * v.w;
  for (int m = 32; m >= 1; m >>= 1) { s += __shfl_xor(s, m); s2 += __shfl_xor(s2, m); }
  __shared__ float sa[4], sb[4];
  if ((t & 63) == 0) { sa[t >> 6] = s; sb[t >> 6] = s2; }
  __syncthreads();
  float S = sa[0] + sa[1] + sa[2] + sa[3];
  float S2 = sb[0] + sb[1] + sb[2] + sb[3];
  float mu = S * (1.f / HDIM);
  float var = S2 * (1.f / HDIM) - mu * mu;
  float inv = rsqrtf(var + 1e-5f);
  float4 gv = ((const float4*)g)[t];
  float4 bv = ((const float4*)bta)[t];
  f16x4 o;
  o[0] = (f16)((v.x - mu) * inv * gv.x + bv.x);
  o[1] = (f16)((v.y - mu) * inv * gv.y + bv.y);
  o[2] = (f16)((v.z - mu) * inv * gv.z + bv.z);
  o[3] = (f16)((v.w - mu) * inv * gv.w + bv.w);
  ((f16x4*)(out + (size_t)row * HDIM))[t] = o;
}

// ---------------- main NT GEMM: C[M,N] = A[M,K] @ BT[N,K]^T + bias ----------------
// 128x128 tile, 4 waves (2x2 of 64x64), BK=32, m97-style global_load_lds staging.
// EPI: 0 = relu -> f16, 1 = f16, 2 = fp32, 3 = fp32 += existing (residual in-place)
template <int EPI>
__global__ __launch_bounds__(256) void gemm_nt(
    const f16* __restrict__ A, const f16* __restrict__ BT,
    const float* __restrict__ bias, void* __restrict__ Cout, int N, int K) {
  __shared__ __align__(16) f16 As[128 * 32];
  __shared__ __align__(16) f16 Bs[128 * 32];
  const int tid = threadIdx.x;
  const int wave = tid >> 6, lane = tid & 63;
  const int l15 = lane & 15, quad = lane >> 4;
  const int bm = blockIdx.x, bn = blockIdx.y;
  const int wm = wave >> 1, wn = wave & 1;

  f32x4 z4 = {0.f, 0.f, 0.f, 0.f};
  f32x4 acc[4][4];
#pragma unroll
  for (int i = 0; i < 4; i++)
#pragma unroll
    for (int j = 0; j < 4; j++) acc[i][j] = z4;

  const f16* Ag = A + (size_t)(bm * 128 + wave * 16 + (lane >> 2)) * K + (lane & 3) * 8;
  const f16* Bg = BT + (size_t)(bn * 128 + wave * 16 + (lane >> 2)) * K + (lane & 3) * 8;
  f16* Al0 = As + wave * 16 * 32;
  f16* Al1 = As + (64 + wave * 16) * 32;
  f16* Bl0 = Bs + wave * 16 * 32;
  f16* Bl1 = Bs + (64 + wave * 16) * 32;
  const size_t kstep = (size_t)64 * K;

  for (int k0 = 0; k0 < K; k0 += 32) {
    async_copy16(Ag, Al0);
    async_copy16(Ag + kstep, Al1);
    async_copy16(Bg, Bl0);
    async_copy16(Bg + kstep, Bl1);
    Ag += 32; Bg += 32;
    __syncthreads();
    f16x8 af[4], bfr[4];
#pragma unroll
    for (int t = 0; t < 4; t++)
      af[t] = *(const f16x8*)&As[(wm * 64 + t * 16 + l15) * 32 + quad * 8];
#pragma unroll
    for (int t = 0; t < 4; t++)
      bfr[t] = *(const f16x8*)&Bs[(wn * 64 + t * 16 + l15) * 32 + quad * 8];
#pragma unroll
    for (int i = 0; i < 4; i++)
#pragma unroll
      for (int j = 0; j < 4; j++)
        acc[i][j] = __builtin_amdgcn_mfma_f32_16x16x32_f16(af[i], bfr[j], acc[i][j], 0, 0, 0);
    __syncthreads();
  }

  float* Cf = (float*)Cout;
  f16* Ch = (f16*)Cout;
#pragma unroll
  for (int i = 0; i < 4; i++) {
    int r0 = bm * 128 + wm * 64 + i * 16 + quad * 4;
#pragma unroll
    for (int j = 0; j < 4; j++) {
      int c = bn * 128 + wn * 64 + j * 16 + l15;
      float bv = bias[c];
#pragma unroll
      for (int reg = 0; reg < 4; reg++) {
        size_t idx = (size_t)(r0 + reg) * N + c;
        float v = acc[i][j][reg] + bv;
        if (EPI == 0)      Ch[idx] = (f16)fmaxf(v, 0.f);
        else if (EPI == 1) Ch[idx] = (f16)v;
        else if (EPI == 2) Cf[idx] = v;
        else               { float rv = Cf[idx]; Cf[idx] = v + rv; }
      }
    }
  }
}

// ---------------- flash attention with zeroed-diagonal scores ----------------
// grid: 2048 = qc(4) x h(8) x b(64). 256 thr / 4 waves; wave owns 32 q-rows.
// K-tiles of 64. Padded LDS rows (136/72 elems) -> conflict-free ds_read_b128.
__global__ __launch_bounds__(256) void attn_kernel(
    const f16* __restrict__ qkv, const f16* __restrict__ vT,
    f16* __restrict__ ctx) {
  const int tid = threadIdx.x;
  const int wave = tid >> 6, lane = tid & 63;
  const int l15 = lane & 15, quad = lane >> 4;
  const int bidx = blockIdx.x;
  const int qc = bidx & 3, h = (bidx >> 2) & 7, bb = bidx >> 5;

  const f16* Qbase = qkv + (size_t)(bb * SEQ) * QKV_LD + h * 128;
  const f16* Kbase = Qbase + 1024;
  const f16* VTbase = vT + (size_t)(bb * NHEAD + h) * HD * SEQ;

  __shared__ __align__(16) f16 Ks[64 * 136];    // row k: [136] (128 used)
  __shared__ __align__(16) f16 VTs[128 * 72];   // row d: [72] (64 used)
  __shared__ __align__(16) f16 Ps[4 * 32 * 72]; // per-wave 32 x [72] (64 used)

  const int qrow0 = qc * 128 + wave * 32;
  f16x8 qf[2][4];
#pragma unroll
  for (int tm = 0; tm < 2; tm++)
#pragma unroll
    for (int s = 0; s < 4; s++)
      qf[tm][s] = *(const f16x8*)(Qbase + (size_t)(qrow0 + tm * 16 + l15) * QKV_LD + s * 32 + quad * 8);

  f32x4 z4 = {0.f, 0.f, 0.f, 0.f};
  f32x4 O[2][8];
#pragma unroll
  for (int i = 0; i < 2; i++)
#pragma unroll
    for (int j = 0; j < 8; j++) O[i][j] = z4;
  float mrow[2][4], lrow[2][4];
#pragma unroll
  for (int i = 0; i < 2; i++)
#pragma unroll
    for (int r = 0; r < 4; r++) { mrow[i][r] = -1e30f; lrow[i][r] = 0.f; }

  const float scale = 0.08838834764831845f;  // 1/sqrt(128)
  const int trow = tid >> 4, tcol = (tid & 15) * 8;  // K staging coords
  const int vrow = tid >> 3, vcol = (tid & 7) * 8;   // VT staging coords
  f16* Pw = &Ps[wave * 32 * 72];

  for (int kt = 0; kt < 8; kt++) {
    const int krow0 = kt * 64;
    // stage K tile [64 x 128] and VT tile [128 x 64] via registers (padded rows)
#pragma unroll
    for (int i = 0; i < 4; i++) {
      int r = i * 16 + trow;
      f16x8 d = *(const f16x8*)(Kbase + (size_t)(krow0 + r) * QKV_LD + tcol);
      *(f16x8*)&Ks[r * 136 + tcol] = d;
    }
#pragma unroll
    for (int i = 0; i < 4; i++) {
      int d = i * 32 + vrow;
      f16x8 dd = *(const f16x8*)(VTbase + (size_t)d * SEQ + krow0 + vcol);
      *(f16x8*)&VTs[d * 72 + vcol] = dd;
    }
    __syncthreads();

    // S = Q @ K^T   (2x4 tiles of 16x16, K-dim = HD = 128 -> 4 mfma steps)
    f32x4 S[2][4];
#pragma unroll
    for (int i = 0; i < 2; i++)
#pragma unroll
      for (int j = 0; j < 4; j++) S[i][j] = z4;
#pragma unroll
    for (int s = 0; s < 4; s++) {
      f16x8 bfr[4];
#pragma unroll
      for (int tn = 0; tn < 4; tn++)
        bfr[tn] = *(const f16x8*)&Ks[(tn * 16 + l15) * 136 + s * 32 + quad * 8];
#pragma unroll
      for (int tm = 0; tm < 2; tm++)
#pragma unroll
        for (int tn = 0; tn < 4; tn++)
          S[tm][tn] = __builtin_amdgcn_mfma_f32_16x16x32_f16(qf[tm][s], bfr[tn], S[tm][tn], 0, 0, 0);
    }

    // online softmax (rows: C-layout row = quad*4+reg; diag score -> 0, not -inf)
#pragma unroll
    for (int tm = 0; tm < 2; tm++) {
#pragma unroll
      for (int reg = 0; reg < 4; reg++) {
        int qg = qc * 128 + wave * 32 + tm * 16 + quad * 4 + reg;
        float mx = -1e30f;
#pragma unroll
        for (int tn = 0; tn < 4; tn++) {
          float v = S[tm][tn][reg] * scale;
          int kg = krow0 + tn * 16 + l15;
          if (kg == qg) v = 0.f;
          S[tm][tn][reg] = v;
          mx = fmaxf(mx, v);
        }
        for (int m = 8; m >= 1; m >>= 1) mx = fmaxf(mx, __shfl_xor(mx, m));
        float mnew = fmaxf(mrow[tm][reg], mx);
        float alpha = __expf(mrow[tm][reg] - mnew);
        mrow[tm][reg] = mnew;
        float rs = 0.f;
#pragma unroll
        for (int tn = 0; tn < 4; tn++) {
          float p = __expf(S[tm][tn][reg] - mnew);
          S[tm][tn][reg] = p;
          rs += p;
        }
        for (int m = 8; m >= 1; m >>= 1) rs += __shfl_xor(rs, m);
        lrow[tm][reg] = lrow[tm][reg] * alpha + rs;
#pragma unroll
        for (int tn = 0; tn < 8; tn++) O[tm][tn][reg] *= alpha;
      }
    }

    // P: C-layout -> LDS -> A-layout
#pragma unroll
    for (int tm = 0; tm < 2; tm++)
#pragma unroll
      for (int reg = 0; reg < 4; reg++)
#pragma unroll
        for (int tn = 0; tn < 4; tn++)
          Pw[(tm * 16 + quad * 4 + reg) * 72 + tn * 16 + l15] = (f16)S[tm][tn][reg];
    __syncthreads();

    // O += P @ V  (V as VT rows: NT gemm; K-dim = 64 -> 2 mfma steps)
#pragma unroll
    for (int ks = 0; ks < 2; ks++) {
      f16x8 pa[2];
#pragma unroll
      for (int tm = 0; tm < 2; tm++)
        pa[tm] = *(const f16x8*)&Pw[(tm * 16 + l15) * 72 + ks * 32 + quad * 8];
#pragma unroll
      for (int tn = 0; tn < 8; tn++) {
        f16x8 vb = *(const f16x8*)&VTs[(tn * 16 + l15) * 72 + ks * 32 + quad * 8];
#pragma unroll
        for (int tm = 0; tm < 2; tm++)
          O[tm][tn] = __builtin_amdgcn_mfma_f32_16x16x32_f16(pa[tm], vb, O[tm][tn], 0, 0, 0);
      }
    }
    __syncthreads();
  }

  // epilogue: O / l -> ctx [B*M, H] (head-major cols)
#pragma unroll
  for (int tm = 0; tm < 2; tm++)
#pragma unroll
    for (int reg = 0; reg < 4; reg++) {
      float inv = 1.f / lrow[tm][reg];
      int row = bb * SEQ + qc * 128 + wave * 32 + tm * 16 + quad * 4 + reg;
#pragma unroll
      for (int tn = 0; tn < 8; tn++) {
        int col = h * 128 + tn * 16 + l15;
        ctx[(size_t)row * HDIM + col] = (f16)(O[tm][tn][reg] * inv);
      }
    }
}

// ---------------- launch ----------------

extern "C" void kernel_launch(void* const* d_in, const int* in_sizes, int n_in,
                              void* d_out, int out_size, void* d_ws, size_t ws_size,
                              hipStream_t stream) {
  (void)in_sizes; (void)n_in; (void)out_size; (void)ws_size;
  const float* x      = (const float*)d_in[0];
  const float* conv_w = (const float*)d_in[1];
  const float* conv_b = (const float*)d_in[2];
  const float* w1     = (const float*)d_in[3];
  const float* b1     = (const float*)d_in[4];
  const float* w2     = (const float*)d_in[5];
  const float* b2     = (const float*)d_in[6];
  const float* ln_g   = (const float*)d_in[7];
  const float* ln_b   = (const float*)d_in[8];
  const float* wq     = (const float*)d_in[9];
  const float* bq     = (const float*)d_in[10];
  const float* wk     = (const float*)d_in[11];
  const float* bk     = (const float*)d_in[12];
  const float* wv     = (const float*)d_in[13];
  const float* bv     = (const float*)d_in[14];
  const float* wo     = (const float*)d_in[15];
  const float* bo     = (const float*)d_in[16];
  const float* wp     = (const float*)d_in[17];
  const float* bp     = (const float*)d_in[18];
  float* out = (float*)d_out;

  char* ws = (char*)d_ws;
  size_t off = 0;
  auto alloc = [&](size_t bytes) {
    char* p = ws + off;
    off += (bytes + 255) & ~(size_t)255;
    return p;
  };
  float* cs   = (float*)alloc(8);
  f16* w1T    = (f16*)alloc((size_t)1024 * 512 * 2);
  f16* w2T    = (f16*)alloc((size_t)1024 * 1024 * 2);
  f16* qkvT   = (f16*)alloc((size_t)3072 * 1024 * 2);
  f16* woT    = (f16*)alloc((size_t)1024 * 1024 * 2);
  f16* wpT    = (f16*)alloc((size_t)1024 * 1024 * 2);
  float* bqkv = (float*)alloc((size_t)3072 * 4);
  f16* qkv    = (f16*)alloc((size_t)MR * 3072 * 2);  // 192 MB; front reused as xh
  f16* h1     = (f16*)alloc((size_t)MR * 1024 * 2);  // 64 MB; reused as vT, then a1
  f16* x_norm = (f16*)alloc((size_t)MR * 1024 * 2);  // 64 MB; reused as ctx
  f16* xh = qkv;   // [32768,512] dead before qkv is written
  f16* vT = h1;    // h1 dead after gemm2
  f16* a1 = h1;    // vT dead after attention
  f16* ctx = x_norm;  // x_norm dead after QKV gemm
  // x_reg (fp32) lives in d_out; final gemm adds residual in-place.

  dim3 tb(32, 8);
  conv_reduce<<<1, 256, 0, stream>>>(conv_w, conv_b, cs);
  transpose_cast<<<dim3(32, 16), tb, 0, stream>>>(w1, w1T, 512, 1024);
  transpose_cast<<<dim3(32, 32), tb, 0, stream>>>(w2, w2T, 1024, 1024);
  transpose_cast<<<dim3(32, 32), tb, 0, stream>>>(wq, qkvT, 1024, 1024);
  transpose_cast<<<dim3(32, 32), tb, 0, stream>>>(wk, qkvT + (size_t)1024 * 1024, 1024, 1024);
  transpose_cast<<<dim3(32, 32), tb, 0, stream>>>(wv, qkvT + (size_t)2048 * 1024, 1024, 1024);
  transpose_cast<<<dim3(32, 32), tb, 0, stream>>>(wo, woT, 1024, 1024);
  transpose_cast<<<dim3(32, 32), tb, 0, stream>>>(wp, wpT, 1024, 1024);
  concat_bias<<<12, 256, 0, stream>>>(bq, bk, bv, bqkv);
  prep_x<<<16384, 256, 0, stream>>>(x, cs, xh);

  gemm_nt<0><<<dim3(256, 8),  256, 0, stream>>>(xh, w1T, b1, (void*)h1, 1024, 512);
  gemm_nt<2><<<dim3(256, 8),  256, 0, stream>>>(h1, w2T, b2, (void*)out, 1024, 1024);   // x_reg -> d_out
  ln_kernel<<<32768, 256, 0, stream>>>(out, ln_g, ln_b, x_norm);
  gemm_nt<1><<<dim3(256, 24), 256, 0, stream>>>(x_norm, qkvT, bqkv, (void*)qkv, 3072, 1024);
  transpose_v<<<dim3(16, 4, 512), tb, 0, stream>>>(qkv, vT);
  attn_kernel<<<2048, 256, 0, stream>>>(qkv, vT, ctx);
  gemm_nt<1><<<dim3(256, 8), 256, 0, stream>>>(ctx, woT, bo, (void*)a1, 1024, 1024);
  gemm_nt<3><<<dim3(256, 8), 256, 0, stream>>>(a1, wpT, bp, (void*)out, 1024, 1024);    // + x_reg residual
}

// Round 2
// 1154.622 us; speedup vs baseline: 1.1469x; 1.1469x over previous
//
#include <hip/hip_runtime.h>
#include <hip/hip_fp16.h>
#include <cstdint>
#include <cstddef>

typedef _Float16 f16;
typedef _Float16 f16x8 __attribute__((ext_vector_type(8)));
typedef _Float16 f16x4 __attribute__((ext_vector_type(4)));
typedef float f32x4 __attribute__((ext_vector_type(4)));

#define NB 64
#define SEQ 512
#define HDIM 1024
#define NHEAD 8
#define HD 128
#define MR (NB * SEQ)      // 32768 rows
#define QKV_LD 3072

// async 16B/lane global->LDS. LDS dest = wave-uniform base + lane*16.
__device__ __forceinline__ void async_copy16(const f16* g, f16* l) {
  __builtin_amdgcn_global_load_lds(
      (__attribute__((address_space(1))) void*)(void*)const_cast<f16*>(g),
      (__attribute__((address_space(3))) void*)l, 16, 0, 0);
}

// ---------------- small prep kernels ----------------

__global__ __launch_bounds__(256) void conv_reduce(
    const float* __restrict__ cw, const float* __restrict__ cb,
    float* __restrict__ out2) {
  int t = threadIdx.x;
  float a = 0.f, b = 0.f;
  for (int i = t; i < HDIM; i += 256) { a += cw[i]; b += cb[i]; }
  for (int m = 32; m >= 1; m >>= 1) { a += __shfl_xor(a, m); b += __shfl_xor(b, m); }
  __shared__ float sa[4], sb[4];
  if ((t & 63) == 0) { sa[t >> 6] = a; sb[t >> 6] = b; }
  __syncthreads();
  if (t == 0) {
    out2[0] = (sa[0] + sa[1] + sa[2] + sa[3]) * (1.f / HDIM);
    out2[1] = (sb[0] + sb[1] + sb[2] + sb[3]) * (1.f / HDIM);
  }
}

// y = x*(1+mean(conv_w)) + mean(conv_b), cast f16. 4 elems/thread.
__global__ __launch_bounds__(256) void prep_x(
    const float* __restrict__ x, const float* __restrict__ cs,
    f16* __restrict__ xh) {
  size_t i = (size_t)blockIdx.x * 256 + threadIdx.x;
  float cw = 1.f + cs[0], cb = cs[1];
  float4 v = ((const float4*)x)[i];
  f16x4 o;
  o[0] = (f16)(v.x * cw + cb);
  o[1] = (f16)(v.y * cw + cb);
  o[2] = (f16)(v.z * cw + cb);
  o[3] = (f16)(v.w * cw + cb);
  ((f16x4*)xh)[i] = o;
}

__global__ __launch_bounds__(256) void concat_bias(
    const float* __restrict__ bq, const float* __restrict__ bk,
    const float* __restrict__ bv, float* __restrict__ dst) {
  int i = blockIdx.x * 256 + threadIdx.x;  // 3072
  if (i < 1024) dst[i] = bq[i];
  else if (i < 2048) dst[i] = bk[i - 1024];
  else dst[i] = bv[i - 2048];
}

// W [K,N] fp32 -> WT [N,K] f16 (NT-gemm weight layout)
__global__ __launch_bounds__(256) void transpose_cast(
    const float* __restrict__ src, f16* __restrict__ dst, int K, int N) {
  __shared__ float tile[32][33];
  int tx = threadIdx.x, ty = threadIdx.y;
  int n0 = blockIdx.x * 32, k0 = blockIdx.y * 32;
#pragma unroll
  for (int r = 0; r < 32; r += 8) tile[ty + r][tx] = src[(size_t)(k0 + ty + r) * N + n0 + tx];
  __syncthreads();
#pragma unroll
  for (int r = 0; r < 32; r += 8)
    dst[(size_t)(n0 + ty + r) * K + k0 + tx] = (f16)tile[tx][ty + r];
}

// v section of qkv [m, 2048 + h*128 + d] -> vT[(b*8+h)*128 + d][m]
__global__ __launch_bounds__(256) void transpose_v(
    const f16* __restrict__ qkv, f16* __restrict__ vT) {
  __shared__ f16 tile[32][33];
  int tx = threadIdx.x, ty = threadIdx.y;
  int m0 = blockIdx.x * 32, d0 = blockIdx.y * 32;
  int bh = blockIdx.z;
  int bb = bh >> 3, h = bh & 7;
  const f16* src = qkv + (size_t)(bb * SEQ) * QKV_LD + 2048 + h * 128;
#pragma unroll
  for (int r = 0; r < 32; r += 8) tile[ty + r][tx] = src[(size_t)(m0 + ty + r) * QKV_LD + d0 + tx];
  __syncthreads();
  f16* dstp = vT + (size_t)bh * HD * SEQ;
#pragma unroll
  for (int r = 0; r < 32; r += 8)
    dstp[(size_t)(d0 + ty + r) * SEQ + m0 + tx] = tile[tx][ty + r];
}

// LayerNorm over H=1024, fp32 in (x_reg), f16 out (x_norm)
__global__ __launch_bounds__(256) void ln_kernel(
    const float* __restrict__ xin, const float* __restrict__ g,
    const float* __restrict__ bta, f16* __restrict__ out) {
  int row = blockIdx.x;
  int t = threadIdx.x;
  float4 v = ((const float4*)(xin + (size_t)row * HDIM))[t];
  float s = v.x + v.y + v.z + v.w;
  float s2 = v.x * v.x + v.y * v.y + v.z * v.z + v.w * v.w;
  for (int m = 32; m >= 1; m >>= 1) { s += __shfl_xor(s, m); s2 += __shfl_xor(s2, m); }
  __shared__ float sa[4], sb[4];
  if ((t & 63) == 0) { sa[t >> 6] = s; sb[t >> 6] = s2; }
  __syncthreads();
  float S = sa[0] + sa[1] + sa[2] + sa[3];
  float S2 = sb[0] + sb[1] + sb[2] + sb[3];
  float mu = S * (1.f / HDIM);
  float var = S2 * (1.f / HDIM) - mu * mu;
  float inv = rsqrtf(var + 1e-5f);
  float4 gv = ((const float4*)g)[t];
  float4 bv = ((const float4*)bta)[t];
  f16x4 o;
  o[0] = (f16)((v.x - mu) * inv * gv.x + bv.x);
  o[1] = (f16)((v.y - mu) * inv * gv.y + bv.y);
  o[2] = (f16)((v.z - mu) * inv * gv.z + bv.z);
  o[3] = (f16)((v.w - mu) * inv * gv.w + bv.w);
  ((f16x4*)(out + (size_t)row * HDIM))[t] = o;
}

// ---------------- main NT GEMM: C[M,N] = A[M,K] @ BT[N,K]^T + bias ----------------
// 128x128 tile, 4 waves (2x2 of 64x64), BK=32, global_load_lds staging.
// LDS chunk rotation: row r's four 16B chunks stored rotated by (r>>1)&3 so
// ds_read_b128 fragment reads hit each 4-bank group exactly 2x (free, m136).
// 1D grid with GROUP=8 bm-swizzle (bn-inner) for L2 locality.
// EPI: 0 = relu -> f16, 1 = f16, 2 = fp32, 3 = fp32 += existing (residual in-place)
template <int EPI>
__global__ __launch_bounds__(256) void gemm_nt(
    const f16* __restrict__ A, const f16* __restrict__ BT,
    const float* __restrict__ bias, void* __restrict__ Cout, int N, int K) {
  __shared__ __align__(16) f16 As[128 * 32];
  __shared__ __align__(16) f16 Bs[128 * 32];
  const int tid = threadIdx.x;
  const int wave = tid >> 6, lane = tid & 63;
  const int l15 = lane & 15, quad = lane >> 4;

  // block swizzle: groups of 8 bm, bn inner
  const int gn = N >> 7;
  const int pid = blockIdx.x;
  const int npg = 8 * gn;
  const int gid = pid / npg;
  const int loc = pid - gid * npg;
  const int bm = gid * 8 + (loc & 7);
  const int bn = loc >> 3;

  const int wm = wave >> 1, wn = wave & 1;

  f32x4 z4 = {0.f, 0.f, 0.f, 0.f};
  f32x4 acc[4][4];
#pragma unroll
  for (int i = 0; i < 4; i++)
#pragma unroll
    for (int j = 0; j < 4; j++) acc[i][j] = z4;

  // source chunk rotated so physical slot (lane&3) holds logical chunk (slot - rot)
  const int rot = (lane >> 3) & 3;                     // ((row_in_tile)>>1)&3
  const int srcChunk = ((lane & 3) + 4 - rot) & 3;
  const f16* Ag = A + (size_t)(bm * 128 + wave * 16 + (lane >> 2)) * K + srcChunk * 8;
  const f16* Bg = BT + (size_t)(bn * 128 + wave * 16 + (lane >> 2)) * K + srcChunk * 8;
  f16* Al0 = As + wave * 16 * 32;
  f16* Al1 = As + (64 + wave * 16) * 32;
  f16* Bl0 = Bs + wave * 16 * 32;
  f16* Bl1 = Bs + (64 + wave * 16) * 32;
  const size_t kstep = (size_t)64 * K;

  const int rrot = (l15 >> 1) & 3;  // fragment-read inverse rotation

  for (int k0 = 0; k0 < K; k0 += 32) {
    async_copy16(Ag, Al0);
    async_copy16(Ag + kstep, Al1);
    async_copy16(Bg, Bl0);
    async_copy16(Bg + kstep, Bl1);
    Ag += 32; Bg += 32;
    __syncthreads();
    f16x8 af[4], bfr[4];
#pragma unroll
    for (int t = 0; t < 4; t++) {
      int slot = (quad + rrot) & 3;
      af[t] = *(const f16x8*)&As[(wm * 64 + t * 16 + l15) * 32 + slot * 8];
      bfr[t] = *(const f16x8*)&Bs[(wn * 64 + t * 16 + l15) * 32 + slot * 8];
    }
#pragma unroll
    for (int i = 0; i < 4; i++)
#pragma unroll
      for (int j = 0; j < 4; j++)
        acc[i][j] = __builtin_amdgcn_mfma_f32_16x16x32_f16(af[i], bfr[j], acc[i][j], 0, 0, 0);
    __syncthreads();
  }

  float* Cf = (float*)Cout;
  f16* Ch = (f16*)Cout;
#pragma unroll
  for (int i = 0; i < 4; i++) {
    int r0 = bm * 128 + wm * 64 + i * 16 + quad * 4;
#pragma unroll
    for (int j = 0; j < 4; j++) {
      int c = bn * 128 + wn * 64 + j * 16 + l15;
      float bv = bias[c];
#pragma unroll
      for (int reg = 0; reg < 4; reg++) {
        size_t idx = (size_t)(r0 + reg) * N + c;
        float v = acc[i][j][reg] + bv;
        if (EPI == 0)      Ch[idx] = (f16)fmaxf(v, 0.f);
        else if (EPI == 1) Ch[idx] = (f16)v;
        else if (EPI == 2) Cf[idx] = v;
        else               { float rv = Cf[idx]; Cf[idx] = v + rv; }
      }
    }
  }
}

// ---------------- flash attention with zeroed-diagonal scores ----------------
// grid: 2048 = qc(4) x h(8) x b(64). 256 thr / 4 waves; wave owns 32 q-rows.
// Fixed-max softmax (scores are O(1): p=exp(s), diag->1) — no online max/alpha.
// Ps is wave-private: no barrier between P write and PV, just lgkmcnt wait.
__global__ __launch_bounds__(256) void attn_kernel(
    const f16* __restrict__ qkv, const f16* __restrict__ vT,
    f16* __restrict__ ctx) {
  const int tid = threadIdx.x;
  const int wave = tid >> 6, lane = tid & 63;
  const int l15 = lane & 15, quad = lane >> 4;
  const int bidx = blockIdx.x;
  const int qc = bidx & 3, h = (bidx >> 2) & 7, bb = bidx >> 5;

  const f16* Qbase = qkv + (size_t)(bb * SEQ) * QKV_LD + h * 128;
  const f16* Kbase = Qbase + 1024;
  const f16* VTbase = vT + (size_t)(bb * NHEAD + h) * HD * SEQ;

  __shared__ __align__(16) f16 Ks[64 * 136];    // row k: [136] (128 used)
  __shared__ __align__(16) f16 VTs[128 * 72];   // row d: [72] (64 used)
  __shared__ __align__(16) f16 Ps[4 * 32 * 72]; // per-wave 32 x [72] (64 used)

  const float scale = 0.08838834764831845f;  // 1/sqrt(128)
  const int qrow0 = qc * 128 + wave * 32;
  f16x8 qf[2][4];
#pragma unroll
  for (int tm = 0; tm < 2; tm++)
#pragma unroll
    for (int s = 0; s < 4; s++) {
      qf[tm][s] = *(const f16x8*)(Qbase + (size_t)(qrow0 + tm * 16 + l15) * QKV_LD + s * 32 + quad * 8);
#pragma unroll
      for (int e = 0; e < 8; e++) qf[tm][s][e] *= (f16)scale;  // fold 1/sqrt(HD) into Q
    }

  f32x4 z4 = {0.f, 0.f, 0.f, 0.f};
  f32x4 O[2][8];
#pragma unroll
  for (int i = 0; i < 2; i++)
#pragma unroll
    for (int j = 0; j < 8; j++) O[i][j] = z4;
  float lrow[2][4];
#pragma unroll
  for (int i = 0; i < 2; i++)
#pragma unroll
    for (int r = 0; r < 4; r++) lrow[i][r] = 0.f;

  const int trow = tid >> 4, tcol = (tid & 15) * 8;  // K staging coords
  const int vrow = tid >> 3, vcol = (tid & 7) * 8;   // VT staging coords
  f16* Pw = &Ps[wave * 32 * 72];

  for (int kt = 0; kt < 8; kt++) {
    const int krow0 = kt * 64;
    // stage K tile [64 x 128] and VT tile [128 x 64] via registers (padded rows)
#pragma unroll
    for (int i = 0; i < 4; i++) {
      int r = i * 16 + trow;
      f16x8 d = *(const f16x8*)(Kbase + (size_t)(krow0 + r) * QKV_LD + tcol);
      *(f16x8*)&Ks[r * 136 + tcol] = d;
    }
#pragma unroll
    for (int i = 0; i < 4; i++) {
      int d = i * 32 + vrow;
      f16x8 dd = *(const f16x8*)(VTbase + (size_t)d * SEQ + krow0 + vcol);
      *(f16x8*)&VTs[d * 72 + vcol] = dd;
    }
    __syncthreads();

    // S = Q @ K^T   (2x4 tiles of 16x16, K-dim = HD = 128 -> 4 mfma steps)
    f32x4 S[2][4];
#pragma unroll
    for (int i = 0; i < 2; i++)
#pragma unroll
      for (int j = 0; j < 4; j++) S[i][j] = z4;
#pragma unroll
    for (int s = 0; s < 4; s++) {
      f16x8 bfr[4];
#pragma unroll
      for (int tn = 0; tn < 4; tn++)
        bfr[tn] = *(const f16x8*)&Ks[(tn * 16 + l15) * 136 + s * 32 + quad * 8];
#pragma unroll
      for (int tm = 0; tm < 2; tm++)
#pragma unroll
        for (int tn = 0; tn < 4; tn++)
          S[tm][tn] = __builtin_amdgcn_mfma_f32_16x16x32_f16(qf[tm][s], bfr[tn], S[tm][tn], 0, 0, 0);
    }

    // fixed-max softmax (C-layout row = quad*4+reg; diag score -> exp(0)=1)
#pragma unroll
    for (int tm = 0; tm < 2; tm++) {
#pragma unroll
      for (int reg = 0; reg < 4; reg++) {
        int qg = qrow0 + tm * 16 + quad * 4 + reg;
        float rs = 0.f;
#pragma unroll
        for (int tn = 0; tn < 4; tn++) {
          int kg = krow0 + tn * 16 + l15;
          float p = (kg == qg) ? 1.f : __expf(S[tm][tn][reg]);
          S[tm][tn][reg] = p;
          rs += p;
        }
        rs += __shfl_xor(rs, 1); rs += __shfl_xor(rs, 2);
        rs += __shfl_xor(rs, 4); rs += __shfl_xor(rs, 8);
        lrow[tm][reg] += rs;
      }
    }

    // P: C-layout -> LDS (wave-private) -> A-layout
#pragma unroll
    for (int tm = 0; tm < 2; tm++)
#pragma unroll
      for (int reg = 0; reg < 4; reg++)
#pragma unroll
        for (int tn = 0; tn < 4; tn++)
          Pw[(tm * 16 + quad * 4 + reg) * 72 + tn * 16 + l15] = (f16)S[tm][tn][reg];
    asm volatile("s_waitcnt lgkmcnt(0)" ::: "memory");  // own-wave LDS writes visible

    // O += P @ V  (V as VT rows: NT gemm; K-dim = 64 -> 2 mfma steps)
#pragma unroll
    for (int ks = 0; ks < 2; ks++) {
      f16x8 pa[2];
#pragma unroll
      for (int tm = 0; tm < 2; tm++)
        pa[tm] = *(const f16x8*)&Pw[(tm * 16 + l15) * 72 + ks * 32 + quad * 8];
#pragma unroll
      for (int tn = 0; tn < 8; tn++) {
        f16x8 vb = *(const f16x8*)&VTs[(tn * 16 + l15) * 72 + ks * 32 + quad * 8];
#pragma unroll
        for (int tm = 0; tm < 2; tm++)
          O[tm][tn] = __builtin_amdgcn_mfma_f32_16x16x32_f16(pa[tm], vb, O[tm][tn], 0, 0, 0);
      }
    }
    __syncthreads();
  }

  // epilogue: O / l -> ctx [B*M, H] (head-major cols)
#pragma unroll
  for (int tm = 0; tm < 2; tm++)
#pragma unroll
    for (int reg = 0; reg < 4; reg++) {
      float inv = 1.f / lrow[tm][reg];
      int row = bb * SEQ + qc * 128 + wave * 32 + tm * 16 + quad * 4 + reg;
#pragma unroll
      for (int tn = 0; tn < 8; tn++) {
        int col = h * 128 + tn * 16 + l15;
        ctx[(size_t)row * HDIM + col] = (f16)(O[tm][tn][reg] * inv);
      }
    }
}

// ---------------- launch ----------------

extern "C" void kernel_launch(void* const* d_in, const int* in_sizes, int n_in,
                              void* d_out, int out_size, void* d_ws, size_t ws_size,
                              hipStream_t stream) {
  (void)in_sizes; (void)n_in; (void)out_size; (void)ws_size;
  const float* x      = (const float*)d_in[0];
  const float* conv_w = (const float*)d_in[1];
  const float* conv_b = (const float*)d_in[2];
  const float* w1     = (const float*)d_in[3];
  const float* b1     = (const float*)d_in[4];
  const float* w2     = (const float*)d_in[5];
  const float* b2     = (const float*)d_in[6];
  const float* ln_g   = (const float*)d_in[7];
  const float* ln_b   = (const float*)d_in[8];
  const float* wq     = (const float*)d_in[9];
  const float* bq     = (const float*)d_in[10];
  const float* wk     = (const float*)d_in[11];
  const float* bk     = (const float*)d_in[12];
  const float* wv     = (const float*)d_in[13];
  const float* bv     = (const float*)d_in[14];
  const float* wo     = (const float*)d_in[15];
  const float* bo     = (const float*)d_in[16];
  const float* wp     = (const float*)d_in[17];
  const float* bp     = (const float*)d_in[18];
  float* out = (float*)d_out;

  char* ws = (char*)d_ws;
  size_t off = 0;
  auto alloc = [&](size_t bytes) {
    char* p = ws + off;
    off += (bytes + 255) & ~(size_t)255;
    return p;
  };
  float* cs   = (float*)alloc(8);
  f16* w1T    = (f16*)alloc((size_t)1024 * 512 * 2);
  f16* w2T    = (f16*)alloc((size_t)1024 * 1024 * 2);
  f16* qkvT   = (f16*)alloc((size_t)3072 * 1024 * 2);
  f16* woT    = (f16*)alloc((size_t)1024 * 1024 * 2);
  f16* wpT    = (f16*)alloc((size_t)1024 * 1024 * 2);
  float* bqkv = (float*)alloc((size_t)3072 * 4);
  f16* qkv    = (f16*)alloc((size_t)MR * 3072 * 2);  // 192 MB; front reused as xh
  f16* h1     = (f16*)alloc((size_t)MR * 1024 * 2);  // 64 MB; reused as vT, then a1
  f16* x_norm = (f16*)alloc((size_t)MR * 1024 * 2);  // 64 MB; reused as ctx
  f16* xh = qkv;   // [32768,512] dead before qkv is written
  f16* vT = h1;    // h1 dead after gemm2
  f16* a1 = h1;    // vT dead after attention
  f16* ctx = x_norm;  // x_norm dead after QKV gemm
  // x_reg (fp32) lives in d_out; final gemm adds residual in-place.

  dim3 tb(32, 8);
  conv_reduce<<<1, 256, 0, stream>>>(conv_w, conv_b, cs);
  transpose_cast<<<dim3(32, 16), tb, 0, stream>>>(w1, w1T, 512, 1024);
  transpose_cast<<<dim3(32, 32), tb, 0, stream>>>(w2, w2T, 1024, 1024);
  transpose_cast<<<dim3(32, 32), tb, 0, stream>>>(wq, qkvT, 1024, 1024);
  transpose_cast<<<dim3(32, 32), tb, 0, stream>>>(wk, qkvT + (size_t)1024 * 1024, 1024, 1024);
  transpose_cast<<<dim3(32, 32), tb, 0, stream>>>(wv, qkvT + (size_t)2048 * 1024, 1024, 1024);
  transpose_cast<<<dim3(32, 32), tb, 0, stream>>>(wo, woT, 1024, 1024);
  transpose_cast<<<dim3(32, 32), tb, 0, stream>>>(wp, wpT, 1024, 1024);
  concat_bias<<<12, 256, 0, stream>>>(bq, bk, bv, bqkv);
  prep_x<<<16384, 256, 0, stream>>>(x, cs, xh);

  gemm_nt<0><<<dim3(256 * 8),  256, 0, stream>>>(xh, w1T, b1, (void*)h1, 1024, 512);
  gemm_nt<2><<<dim3(256 * 8),  256, 0, stream>>>(h1, w2T, b2, (void*)out, 1024, 1024);   // x_reg -> d_out
  ln_kernel<<<32768, 256, 0, stream>>>(out, ln_g, ln_b, x_norm);
  gemm_nt<1><<<dim3(256 * 24), 256, 0, stream>>>(x_norm, qkvT, bqkv, (void*)qkv, 3072, 1024);
  transpose_v<<<dim3(16, 4, 512), tb, 0, stream>>>(qkv, vT);
  attn_kernel<<<2048, 256, 0, stream>>>(qkv, vT, ctx);
  gemm_nt<1><<<dim3(256 * 8), 256, 0, stream>>>(ctx, woT, bo, (void*)a1, 1024, 1024);
  gemm_nt<3><<<dim3(256 * 8), 256, 0, stream>>>(a1, wpT, bp, (void*)out, 1024, 1024);    // + x_reg residual
}

// Round 3
// 1131.133 us; speedup vs baseline: 1.1707x; 1.0208x over previous
//
#include <hip/hip_runtime.h>
#include <hip/hip_fp16.h>
#include <cstdint>
#include <cstddef>

typedef _Float16 f16;
typedef _Float16 f16x8 __attribute__((ext_vector_type(8)));
typedef _Float16 f16x4 __attribute__((ext_vector_type(4)));
typedef float f32x4 __attribute__((ext_vector_type(4)));

#define NB 64
#define SEQ 512
#define HDIM 1024
#define NHEAD 8
#define HD 128
#define MR (NB * SEQ)      // 32768 rows
#define QKV_LD 3072

// async 16B/lane global->LDS. LDS dest = wave-uniform base + lane*16.
__device__ __forceinline__ void async_copy16(const f16* g, f16* l) {
  __builtin_amdgcn_global_load_lds(
      (__attribute__((address_space(1))) void*)(void*)const_cast<f16*>(g),
      (__attribute__((address_space(3))) void*)l, 16, 0, 0);
}

// ---------------- small prep kernels ----------------

__global__ __launch_bounds__(256) void conv_reduce(
    const float* __restrict__ cw, const float* __restrict__ cb,
    float* __restrict__ out2) {
  int t = threadIdx.x;
  float a = 0.f, b = 0.f;
  for (int i = t; i < HDIM; i += 256) { a += cw[i]; b += cb[i]; }
  for (int m = 32; m >= 1; m >>= 1) { a += __shfl_xor(a, m); b += __shfl_xor(b, m); }
  __shared__ float sa[4], sb[4];
  if ((t & 63) == 0) { sa[t >> 6] = a; sb[t >> 6] = b; }
  __syncthreads();
  if (t == 0) {
    out2[0] = (sa[0] + sa[1] + sa[2] + sa[3]) * (1.f / HDIM);
    out2[1] = (sb[0] + sb[1] + sb[2] + sb[3]) * (1.f / HDIM);
  }
}

// y = x*(1+mean(conv_w)) + mean(conv_b), cast f16. 4 elems/thread.
__global__ __launch_bounds__(256) void prep_x(
    const float* __restrict__ x, const float* __restrict__ cs,
    f16* __restrict__ xh) {
  size_t i = (size_t)blockIdx.x * 256 + threadIdx.x;
  float cw = 1.f + cs[0], cb = cs[1];
  float4 v = ((const float4*)x)[i];
  f16x4 o;
  o[0] = (f16)(v.x * cw + cb);
  o[1] = (f16)(v.y * cw + cb);
  o[2] = (f16)(v.z * cw + cb);
  o[3] = (f16)(v.w * cw + cb);
  ((f16x4*)xh)[i] = o;
}

__global__ __launch_bounds__(256) void concat_bias(
    const float* __restrict__ bq, const float* __restrict__ bk,
    const float* __restrict__ bv, float* __restrict__ dst) {
  int i = blockIdx.x * 256 + threadIdx.x;  // 3072
  if (i < 1024) dst[i] = bq[i];
  else if (i < 2048) dst[i] = bk[i - 1024];
  else dst[i] = bv[i - 2048];
}

// fp32 -> f16 elementwise (no transpose), 4 elems/thread
__global__ __launch_bounds__(256) void cast_f16(
    const float* __restrict__ src, f16* __restrict__ dst) {
  size_t i = (size_t)blockIdx.x * 256 + threadIdx.x;
  float4 v = ((const float4*)src)[i];
  f16x4 o;
  o[0] = (f16)v.x; o[1] = (f16)v.y; o[2] = (f16)v.z; o[3] = (f16)v.w;
  ((f16x4*)dst)[i] = o;
}

// bp2[n] = bp[n] + sum_j bo[j] * wp[j][n]
__global__ __launch_bounds__(256) void fuse_bias(
    const float* __restrict__ bo, const float* __restrict__ wp,
    const float* __restrict__ bp, float* __restrict__ bp2) {
  int n = blockIdx.x * 256 + threadIdx.x;  // 1024
  float s = bp[n];
#pragma unroll 8
  for (int j = 0; j < 1024; j++) s += bo[j] * wp[(size_t)j * 1024 + n];
  bp2[n] = s;
}

// W [K,N] fp32 -> WT [N,K] f16 (NT-gemm weight layout)
__global__ __launch_bounds__(256) void transpose_cast(
    const float* __restrict__ src, f16* __restrict__ dst, int K, int N) {
  __shared__ float tile[32][33];
  int tx = threadIdx.x, ty = threadIdx.y;
  int n0 = blockIdx.x * 32, k0 = blockIdx.y * 32;
#pragma unroll
  for (int r = 0; r < 32; r += 8) tile[ty + r][tx] = src[(size_t)(k0 + ty + r) * N + n0 + tx];
  __syncthreads();
#pragma unroll
  for (int r = 0; r < 32; r += 8)
    dst[(size_t)(n0 + ty + r) * K + k0 + tx] = (f16)tile[tx][ty + r];
}

// v section of qkv [m, 2048 + h*128 + d] -> vT[(b*8+h)*128 + d][m]
__global__ __launch_bounds__(256) void transpose_v(
    const f16* __restrict__ qkv, f16* __restrict__ vT) {
  __shared__ f16 tile[32][33];
  int tx = threadIdx.x, ty = threadIdx.y;
  int m0 = blockIdx.x * 32, d0 = blockIdx.y * 32;
  int bh = blockIdx.z;
  int bb = bh >> 3, h = bh & 7;
  const f16* src = qkv + (size_t)(bb * SEQ) * QKV_LD + 2048 + h * 128;
#pragma unroll
  for (int r = 0; r < 32; r += 8) tile[ty + r][tx] = src[(size_t)(m0 + ty + r) * QKV_LD + d0 + tx];
  __syncthreads();
  f16* dstp = vT + (size_t)bh * HD * SEQ;
#pragma unroll
  for (int r = 0; r < 32; r += 8)
    dstp[(size_t)(d0 + ty + r) * SEQ + m0 + tx] = tile[tx][ty + r];
}

// LayerNorm over H=1024, fp32 in (x_reg), f16 out (x_norm)
__global__ __launch_bounds__(256) void ln_kernel(
    const float* __restrict__ xin, const float* __restrict__ g,
    const float* __restrict__ bta, f16* __restrict__ out) {
  int row = blockIdx.x;
  int t = threadIdx.x;
  float4 v = ((const float4*)(xin + (size_t)row * HDIM))[t];
  float s = v.x + v.y + v.z + v.w;
  float s2 = v.x * v.x + v.y * v.y + v.z * v.z + v.w * v.w;
  for (int m = 32; m >= 1; m >>= 1) { s += __shfl_xor(s, m); s2 += __shfl_xor(s2, m); }
  __shared__ float sa[4], sb[4];
  if ((t & 63) == 0) { sa[t >> 6] = s; sb[t >> 6] = s2; }
  __syncthreads();
  float S = sa[0] + sa[1] + sa[2] + sa[3];
  float S2 = sb[0] + sb[1] + sb[2] + sb[3];
  float mu = S * (1.f / HDIM);
  float var = S2 * (1.f / HDIM) - mu * mu;
  float inv = rsqrtf(var + 1e-5f);
  float4 gv = ((const float4*)g)[t];
  float4 bv = ((const float4*)bta)[t];
  f16x4 o;
  o[0] = (f16)((v.x - mu) * inv * gv.x + bv.x);
  o[1] = (f16)((v.y - mu) * inv * gv.y + bv.y);
  o[2] = (f16)((v.z - mu) * inv * gv.z + bv.z);
  o[3] = (f16)((v.w - mu) * inv * gv.w + bv.w);
  ((f16x4*)(out + (size_t)row * HDIM))[t] = o;
}

// ---------------- main NT GEMM: C[M,N] = A[M,K] @ BT[N,K]^T + bias ----------------
// 128x128 tile, 4 waves (2x2 of 64x64), BK=32, global_load_lds staging.
// LDS chunk rotation (conflict-free, R2-verified). GROUP=16 bm-swizzle, bn inner.
// EPI: 0 = relu->f16, 1 = f16, 2 = fp32, 3 = fp32 += existing, 4 = f16 no-bias
template <int EPI>
__global__ __launch_bounds__(256) void gemm_nt(
    const f16* __restrict__ A, const f16* __restrict__ BT,
    const float* __restrict__ bias, void* __restrict__ Cout, int N, int K) {
  __shared__ __align__(16) f16 As[128 * 32];
  __shared__ __align__(16) f16 Bs[128 * 32];
  const int tid = threadIdx.x;
  const int wave = tid >> 6, lane = tid & 63;
  const int l15 = lane & 15, quad = lane >> 4;

  // block swizzle: groups of up to 16 bm, bn inner
  const int gn = N >> 7;
  const int gm = (int)gridDim.x / gn;
  const int pid = blockIdx.x;
  const int npg = 16 * gn;
  const int gid = pid / npg;
  const int rem = pid - gid * npg;
  const int grows = min(16, gm - gid * 16);
  const int bm = gid * 16 + rem % grows;
  const int bn = rem / grows;

  const int wm = wave >> 1, wn = wave & 1;

  f32x4 z4 = {0.f, 0.f, 0.f, 0.f};
  f32x4 acc[4][4];
#pragma unroll
  for (int i = 0; i < 4; i++)
#pragma unroll
    for (int j = 0; j < 4; j++) acc[i][j] = z4;

  // source chunk rotated so physical slot (lane&3) holds logical chunk (slot - rot)
  const int rot = (lane >> 3) & 3;                     // ((row_in_tile)>>1)&3
  const int srcChunk = ((lane & 3) + 4 - rot) & 3;
  const f16* Ag = A + (size_t)(bm * 128 + wave * 16 + (lane >> 2)) * K + srcChunk * 8;
  const f16* Bg = BT + (size_t)(bn * 128 + wave * 16 + (lane >> 2)) * K + srcChunk * 8;
  f16* Al0 = As + wave * 16 * 32;
  f16* Al1 = As + (64 + wave * 16) * 32;
  f16* Bl0 = Bs + wave * 16 * 32;
  f16* Bl1 = Bs + (64 + wave * 16) * 32;
  const size_t kstep = (size_t)64 * K;

  const int rrot = (l15 >> 1) & 3;  // fragment-read inverse rotation

  for (int k0 = 0; k0 < K; k0 += 32) {
    async_copy16(Ag, Al0);
    async_copy16(Ag + kstep, Al1);
    async_copy16(Bg, Bl0);
    async_copy16(Bg + kstep, Bl1);
    Ag += 32; Bg += 32;
    __syncthreads();
    f16x8 af[4], bfr[4];
#pragma unroll
    for (int t = 0; t < 4; t++) {
      int slot = (quad + rrot) & 3;
      af[t] = *(const f16x8*)&As[(wm * 64 + t * 16 + l15) * 32 + slot * 8];
      bfr[t] = *(const f16x8*)&Bs[(wn * 64 + t * 16 + l15) * 32 + slot * 8];
    }
#pragma unroll
    for (int i = 0; i < 4; i++)
#pragma unroll
      for (int j = 0; j < 4; j++)
        acc[i][j] = __builtin_amdgcn_mfma_f32_16x16x32_f16(af[i], bfr[j], acc[i][j], 0, 0, 0);
    __syncthreads();
  }

  float* Cf = (float*)Cout;
  f16* Ch = (f16*)Cout;
#pragma unroll
  for (int i = 0; i < 4; i++) {
    int r0 = bm * 128 + wm * 64 + i * 16 + quad * 4;
#pragma unroll
    for (int j = 0; j < 4; j++) {
      int c = bn * 128 + wn * 64 + j * 16 + l15;
      float bv = (EPI == 4) ? 0.f : bias[c];
#pragma unroll
      for (int reg = 0; reg < 4; reg++) {
        size_t idx = (size_t)(r0 + reg) * N + c;
        float v = acc[i][j][reg] + bv;
        if (EPI == 0)      Ch[idx] = (f16)fmaxf(v, 0.f);
        else if (EPI == 1) Ch[idx] = (f16)v;
        else if (EPI == 2) Cf[idx] = v;
        else if (EPI == 3) { float rv = Cf[idx]; Cf[idx] = v + rv; }
        else               Ch[idx] = (f16)v;
      }
    }
  }
}

// ---------------- flash attention with zeroed-diagonal scores ----------------
// grid: 2048 = qc(4) x h(8) x b(64). 256 thr / 4 waves; wave owns 32 q-rows.
// Fixed-max softmax (scores are O(1): p=exp(s), diag->1) — no online max/alpha.
// Ps is wave-private: no barrier between P write and PV, just lgkmcnt wait.
__global__ __launch_bounds__(256) void attn_kernel(
    const f16* __restrict__ qkv, const f16* __restrict__ vT,
    f16* __restrict__ ctx) {
  const int tid = threadIdx.x;
  const int wave = tid >> 6, lane = tid & 63;
  const int l15 = lane & 15, quad = lane >> 4;
  const int bidx = blockIdx.x;
  const int qc = bidx & 3, h = (bidx >> 2) & 7, bb = bidx >> 5;

  const f16* Qbase = qkv + (size_t)(bb * SEQ) * QKV_LD + h * 128;
  const f16* Kbase = Qbase + 1024;
  const f16* VTbase = vT + (size_t)(bb * NHEAD + h) * HD * SEQ;

  __shared__ __align__(16) f16 Ks[64 * 136];    // row k: [136] (128 used)
  __shared__ __align__(16) f16 VTs[128 * 72];   // row d: [72] (64 used)
  __shared__ __align__(16) f16 Ps[4 * 32 * 72]; // per-wave 32 x [72] (64 used)

  const float scale = 0.08838834764831845f;  // 1/sqrt(128)
  const int qrow0 = qc * 128 + wave * 32;
  f16x8 qf[2][4];
#pragma unroll
  for (int tm = 0; tm < 2; tm++)
#pragma unroll
    for (int s = 0; s < 4; s++) {
      qf[tm][s] = *(const f16x8*)(Qbase + (size_t)(qrow0 + tm * 16 + l15) * QKV_LD + s * 32 + quad * 8);
#pragma unroll
      for (int e = 0; e < 8; e++) qf[tm][s][e] *= (f16)scale;  // fold 1/sqrt(HD) into Q
    }

  f32x4 z4 = {0.f, 0.f, 0.f, 0.f};
  f32x4 O[2][8];
#pragma unroll
  for (int i = 0; i < 2; i++)
#pragma unroll
    for (int j = 0; j < 8; j++) O[i][j] = z4;
  float lrow[2][4];
#pragma unroll
  for (int i = 0; i < 2; i++)
#pragma unroll
    for (int r = 0; r < 4; r++) lrow[i][r] = 0.f;

  const int trow = tid >> 4, tcol = (tid & 15) * 8;  // K staging coords
  const int vrow = tid >> 3, vcol = (tid & 7) * 8;   // VT staging coords
  f16* Pw = &Ps[wave * 32 * 72];

  for (int kt = 0; kt < 8; kt++) {
    const int krow0 = kt * 64;
    // stage K tile [64 x 128] and VT tile [128 x 64] via registers (padded rows)
#pragma unroll
    for (int i = 0; i < 4; i++) {
      int r = i * 16 + trow;
      f16x8 d = *(const f16x8*)(Kbase + (size_t)(krow0 + r) * QKV_LD + tcol);
      *(f16x8*)&Ks[r * 136 + tcol] = d;
    }
#pragma unroll
    for (int i = 0; i < 4; i++) {
      int d = i * 32 + vrow;
      f16x8 dd = *(const f16x8*)(VTbase + (size_t)d * SEQ + krow0 + vcol);
      *(f16x8*)&VTs[d * 72 + vcol] = dd;
    }
    __syncthreads();

    // S = Q @ K^T   (2x4 tiles of 16x16, K-dim = HD = 128 -> 4 mfma steps)
    f32x4 S[2][4];
#pragma unroll
    for (int i = 0; i < 2; i++)
#pragma unroll
      for (int j = 0; j < 4; j++) S[i][j] = z4;
#pragma unroll
    for (int s = 0; s < 4; s++) {
      f16x8 bfr[4];
#pragma unroll
      for (int tn = 0; tn < 4; tn++)
        bfr[tn] = *(const f16x8*)&Ks[(tn * 16 + l15) * 136 + s * 32 + quad * 8];
#pragma unroll
      for (int tm = 0; tm < 2; tm++)
#pragma unroll
        for (int tn = 0; tn < 4; tn++)
          S[tm][tn] = __builtin_amdgcn_mfma_f32_16x16x32_f16(qf[tm][s], bfr[tn], S[tm][tn], 0, 0, 0);
    }

    // fixed-max softmax (C-layout row = quad*4+reg; diag score -> exp(0)=1)
#pragma unroll
    for (int tm = 0; tm < 2; tm++) {
#pragma unroll
      for (int reg = 0; reg < 4; reg++) {
        int qg = qrow0 + tm * 16 + quad * 4 + reg;
        float rs = 0.f;
#pragma unroll
        for (int tn = 0; tn < 4; tn++) {
          int kg = krow0 + tn * 16 + l15;
          float p = (kg == qg) ? 1.f : __expf(S[tm][tn][reg]);
          S[tm][tn][reg] = p;
          rs += p;
        }
        rs += __shfl_xor(rs, 1); rs += __shfl_xor(rs, 2);
        rs += __shfl_xor(rs, 4); rs += __shfl_xor(rs, 8);
        lrow[tm][reg] += rs;
      }
    }

    // P: C-layout -> LDS (wave-private) -> A-layout
#pragma unroll
    for (int tm = 0; tm < 2; tm++)
#pragma unroll
      for (int reg = 0; reg < 4; reg++)
#pragma unroll
        for (int tn = 0; tn < 4; tn++)
          Pw[(tm * 16 + quad * 4 + reg) * 72 + tn * 16 + l15] = (f16)S[tm][tn][reg];
    asm volatile("s_waitcnt lgkmcnt(0)" ::: "memory");  // own-wave LDS writes visible

    // O += P @ V  (V as VT rows: NT gemm; K-dim = 64 -> 2 mfma steps)
#pragma unroll
    for (int ks = 0; ks < 2; ks++) {
      f16x8 pa[2];
#pragma unroll
      for (int tm = 0; tm < 2; tm++)
        pa[tm] = *(const f16x8*)&Pw[(tm * 16 + l15) * 72 + ks * 32 + quad * 8];
#pragma unroll
      for (int tn = 0; tn < 8; tn++) {
        f16x8 vb = *(const f16x8*)&VTs[(tn * 16 + l15) * 72 + ks * 32 + quad * 8];
#pragma unroll
        for (int tm = 0; tm < 2; tm++)
          O[tm][tn] = __builtin_amdgcn_mfma_f32_16x16x32_f16(pa[tm], vb, O[tm][tn], 0, 0, 0);
      }
    }
    __syncthreads();
  }

  // epilogue: O / l -> ctx [B*M, H] (head-major cols)
#pragma unroll
  for (int tm = 0; tm < 2; tm++)
#pragma unroll
    for (int reg = 0; reg < 4; reg++) {
      float inv = 1.f / lrow[tm][reg];
      int row = bb * SEQ + qc * 128 + wave * 32 + tm * 16 + quad * 4 + reg;
#pragma unroll
      for (int tn = 0; tn < 8; tn++) {
        int col = h * 128 + tn * 16 + l15;
        ctx[(size_t)row * HDIM + col] = (f16)(O[tm][tn][reg] * inv);
      }
    }
}

// ---------------- launch ----------------

extern "C" void kernel_launch(void* const* d_in, const int* in_sizes, int n_in,
                              void* d_out, int out_size, void* d_ws, size_t ws_size,
                              hipStream_t stream) {
  (void)in_sizes; (void)n_in; (void)out_size; (void)ws_size;
  const float* x      = (const float*)d_in[0];
  const float* conv_w = (const float*)d_in[1];
  const float* conv_b = (const float*)d_in[2];
  const float* w1     = (const float*)d_in[3];
  const float* b1     = (const float*)d_in[4];
  const float* w2     = (const float*)d_in[5];
  const float* b2     = (const float*)d_in[6];
  const float* ln_g   = (const float*)d_in[7];
  const float* ln_b   = (const float*)d_in[8];
  const float* wq     = (const float*)d_in[9];
  const float* bq     = (const float*)d_in[10];
  const float* wk     = (const float*)d_in[11];
  const float* bk     = (const float*)d_in[12];
  const float* wv     = (const float*)d_in[13];
  const float* bv     = (const float*)d_in[14];
  const float* wo     = (const float*)d_in[15];
  const float* bo     = (const float*)d_in[16];
  const float* wp     = (const float*)d_in[17];
  const float* bp     = (const float*)d_in[18];
  float* out = (float*)d_out;

  char* ws = (char*)d_ws;
  size_t off = 0;
  auto alloc = [&](size_t bytes) {
    char* p = ws + off;
    off += (bytes + 255) & ~(size_t)255;
    return p;
  };
  float* cs   = (float*)alloc(8);
  f16* w1T    = (f16*)alloc((size_t)1024 * 512 * 2);
  f16* w2T    = (f16*)alloc((size_t)1024 * 1024 * 2);
  f16* qkvT   = (f16*)alloc((size_t)3072 * 1024 * 2);
  f16* wpT    = (f16*)alloc((size_t)1024 * 1024 * 2);
  f16* woh    = (f16*)alloc((size_t)1024 * 1024 * 2);  // wo cast f16 row-major
  f16* woPT   = (f16*)alloc((size_t)1024 * 1024 * 2);  // (wo@wp)^T-ish NT layout
  float* bqkv = (float*)alloc((size_t)3072 * 4);
  float* bp2  = (float*)alloc((size_t)1024 * 4);
  f16* qkv    = (f16*)alloc((size_t)MR * 3072 * 2);  // 192 MB; front reused as xh
  f16* h1     = (f16*)alloc((size_t)MR * 1024 * 2);  // 64 MB; reused as vT
  f16* x_norm = (f16*)alloc((size_t)MR * 1024 * 2);  // 64 MB; reused as ctx
  f16* xh = qkv;   // [32768,512] dead before qkv is written
  f16* vT = h1;    // h1 dead after gemm2
  f16* ctx = x_norm;  // x_norm dead after QKV gemm
  // x_reg (fp32) lives in d_out; final gemm adds residual in-place.

  dim3 tb(32, 8);
  conv_reduce<<<1, 256, 0, stream>>>(conv_w, conv_b, cs);
  transpose_cast<<<dim3(32, 16), tb, 0, stream>>>(w1, w1T, 512, 1024);
  transpose_cast<<<dim3(32, 32), tb, 0, stream>>>(w2, w2T, 1024, 1024);
  transpose_cast<<<dim3(32, 32), tb, 0, stream>>>(wq, qkvT, 1024, 1024);
  transpose_cast<<<dim3(32, 32), tb, 0, stream>>>(wk, qkvT + (size_t)1024 * 1024, 1024, 1024);
  transpose_cast<<<dim3(32, 32), tb, 0, stream>>>(wv, qkvT + (size_t)2048 * 1024, 1024, 1024);
  transpose_cast<<<dim3(32, 32), tb, 0, stream>>>(wp, wpT, 1024, 1024);
  cast_f16<<<1024, 256, 0, stream>>>(wo, woh);
  concat_bias<<<12, 256, 0, stream>>>(bq, bk, bv, bqkv);
  fuse_bias<<<4, 256, 0, stream>>>(bo, wp, bp, bp2);
  prep_x<<<16384, 256, 0, stream>>>(x, cs, xh);

  // woPT[n][k] = (wo@wp)[k][n]: C[m=n][n=k] = sum_j wpT[n][j] * woh[k][j]
  gemm_nt<4><<<dim3(64), 256, 0, stream>>>(wpT, woh, nullptr, (void*)woPT, 1024, 1024);

  gemm_nt<0><<<dim3(256 * 8),  256, 0, stream>>>(xh, w1T, b1, (void*)h1, 1024, 512);
  gemm_nt<2><<<dim3(256 * 8),  256, 0, stream>>>(h1, w2T, b2, (void*)out, 1024, 1024);   // x_reg -> d_out
  ln_kernel<<<32768, 256, 0, stream>>>(out, ln_g, ln_b, x_norm);
  gemm_nt<1><<<dim3(256 * 24), 256, 0, stream>>>(x_norm, qkvT, bqkv, (void*)qkv, 3072, 1024);
  transpose_v<<<dim3(16, 4, 512), tb, 0, stream>>>(qkv, vT);
  attn_kernel<<<2048, 256, 0, stream>>>(qkv, vT, ctx);
  // fused wo+wp: out = ctx @ woP + bp2 + x_reg (in-place residual)
  gemm_nt<3><<<dim3(256 * 8), 256, 0, stream>>>(ctx, woPT, bp2, (void*)out, 1024, 1024);
}

// Round 4
// 1086.812 us; speedup vs baseline: 1.2185x; 1.0408x over previous
//
#include <hip/hip_runtime.h>
#include <hip/hip_fp16.h>
#include <cstdint>
#include <cstddef>

typedef _Float16 f16;
typedef _Float16 f16x8 __attribute__((ext_vector_type(8)));
typedef _Float16 f16x4 __attribute__((ext_vector_type(4)));
typedef float f32x4 __attribute__((ext_vector_type(4)));

#define NB 64
#define SEQ 512
#define HDIM 1024
#define NHEAD 8
#define HD 128
#define MR (NB * SEQ)      // 32768 rows
#define QKV_LD 3072

// async 16B/lane global->LDS. LDS dest = wave-uniform base + lane*16.
__device__ __forceinline__ void async_copy16(const f16* g, f16* l) {
  __builtin_amdgcn_global_load_lds(
      (__attribute__((address_space(1))) void*)(void*)const_cast<f16*>(g),
      (__attribute__((address_space(3))) void*)l, 16, 0, 0);
}

// ---------------- small prep kernels ----------------

__global__ __launch_bounds__(256) void conv_reduce(
    const float* __restrict__ cw, const float* __restrict__ cb,
    float* __restrict__ out2) {
  int t = threadIdx.x;
  float a = 0.f, b = 0.f;
  for (int i = t; i < HDIM; i += 256) { a += cw[i]; b += cb[i]; }
  for (int m = 32; m >= 1; m >>= 1) { a += __shfl_xor(a, m); b += __shfl_xor(b, m); }
  __shared__ float sa[4], sb[4];
  if ((t & 63) == 0) { sa[t >> 6] = a; sb[t >> 6] = b; }
  __syncthreads();
  if (t == 0) {
    out2[0] = (sa[0] + sa[1] + sa[2] + sa[3]) * (1.f / HDIM);
    out2[1] = (sb[0] + sb[1] + sb[2] + sb[3]) * (1.f / HDIM);
  }
}

// y = x*(1+mean(conv_w)) + mean(conv_b), cast f16. 4 elems/thread.
__global__ __launch_bounds__(256) void prep_x(
    const float* __restrict__ x, const float* __restrict__ cs,
    f16* __restrict__ xh) {
  size_t i = (size_t)blockIdx.x * 256 + threadIdx.x;
  float cw = 1.f + cs[0], cb = cs[1];
  float4 v = ((const float4*)x)[i];
  f16x4 o;
  o[0] = (f16)(v.x * cw + cb);
  o[1] = (f16)(v.y * cw + cb);
  o[2] = (f16)(v.z * cw + cb);
  o[3] = (f16)(v.w * cw + cb);
  ((f16x4*)xh)[i] = o;
}

__global__ __launch_bounds__(256) void concat_bias(
    const float* __restrict__ bq, const float* __restrict__ bk,
    const float* __restrict__ bv, float* __restrict__ dst) {
  int i = blockIdx.x * 256 + threadIdx.x;  // 3072
  if (i < 1024) dst[i] = bq[i];
  else if (i < 2048) dst[i] = bk[i - 1024];
  else dst[i] = bv[i - 2048];
}

// fp32 -> f16 elementwise (no transpose), 4 elems/thread
__global__ __launch_bounds__(256) void cast_f16(
    const float* __restrict__ src, f16* __restrict__ dst) {
  size_t i = (size_t)blockIdx.x * 256 + threadIdx.x;
  float4 v = ((const float4*)src)[i];
  f16x4 o;
  o[0] = (f16)v.x; o[1] = (f16)v.y; o[2] = (f16)v.z; o[3] = (f16)v.w;
  ((f16x4*)dst)[i] = o;
}

// bp2[n] = bp[n] + sum_j bo[j] * wp[j][n]
__global__ __launch_bounds__(256) void fuse_bias(
    const float* __restrict__ bo, const float* __restrict__ wp,
    const float* __restrict__ bp, float* __restrict__ bp2) {
  int n = blockIdx.x * 256 + threadIdx.x;  // 1024
  float s = bp[n];
#pragma unroll 8
  for (int j = 0; j < 1024; j++) s += bo[j] * wp[(size_t)j * 1024 + n];
  bp2[n] = s;
}

// W [K,N] fp32 -> WT [N,K] f16 (NT-gemm weight layout)
__global__ __launch_bounds__(256) void transpose_cast(
    const float* __restrict__ src, f16* __restrict__ dst, int K, int N) {
  __shared__ float tile[32][33];
  int tx = threadIdx.x, ty = threadIdx.y;
  int n0 = blockIdx.x * 32, k0 = blockIdx.y * 32;
#pragma unroll
  for (int r = 0; r < 32; r += 8) tile[ty + r][tx] = src[(size_t)(k0 + ty + r) * N + n0 + tx];
  __syncthreads();
#pragma unroll
  for (int r = 0; r < 32; r += 8)
    dst[(size_t)(n0 + ty + r) * K + k0 + tx] = (f16)tile[tx][ty + r];
}

// v section of qkv [m, 2048 + h*128 + d] -> vT[(b*8+h)*128 + d][m]
__global__ __launch_bounds__(256) void transpose_v(
    const f16* __restrict__ qkv, f16* __restrict__ vT) {
  __shared__ f16 tile[32][33];
  int tx = threadIdx.x, ty = threadIdx.y;
  int m0 = blockIdx.x * 32, d0 = blockIdx.y * 32;
  int bh = blockIdx.z;
  int bb = bh >> 3, h = bh & 7;
  const f16* src = qkv + (size_t)(bb * SEQ) * QKV_LD + 2048 + h * 128;
#pragma unroll
  for (int r = 0; r < 32; r += 8) tile[ty + r][tx] = src[(size_t)(m0 + ty + r) * QKV_LD + d0 + tx];
  __syncthreads();
  f16* dstp = vT + (size_t)bh * HD * SEQ;
#pragma unroll
  for (int r = 0; r < 32; r += 8)
    dstp[(size_t)(d0 + ty + r) * SEQ + m0 + tx] = tile[tx][ty + r];
}

// LayerNorm over H=1024, fp32 in (x_reg), f16 out (x_norm)
__global__ __launch_bounds__(256) void ln_kernel(
    const float* __restrict__ xin, const float* __restrict__ g,
    const float* __restrict__ bta, f16* __restrict__ out) {
  int row = blockIdx.x;
  int t = threadIdx.x;
  float4 v = ((const float4*)(xin + (size_t)row * HDIM))[t];
  float s = v.x + v.y + v.z + v.w;
  float s2 = v.x * v.x + v.y * v.y + v.z * v.z + v.w * v.w;
  for (int m = 32; m >= 1; m >>= 1) { s += __shfl_xor(s, m); s2 += __shfl_xor(s2, m); }
  __shared__ float sa[4], sb[4];
  if ((t & 63) == 0) { sa[t >> 6] = s; sb[t >> 6] = s2; }
  __syncthreads();
  float S = sa[0] + sa[1] + sa[2] + sa[3];
  float S2 = sb[0] + sb[1] + sb[2] + sb[3];
  float mu = S * (1.f / HDIM);
  float var = S2 * (1.f / HDIM) - mu * mu;
  float inv = rsqrtf(var + 1e-5f);
  float4 gv = ((const float4*)g)[t];
  float4 bv = ((const float4*)bta)[t];
  f16x4 o;
  o[0] = (f16)((v.x - mu) * inv * gv.x + bv.x);
  o[1] = (f16)((v.y - mu) * inv * gv.y + bv.y);
  o[2] = (f16)((v.z - mu) * inv * gv.z + bv.z);
  o[3] = (f16)((v.w - mu) * inv * gv.w + bv.w);
  ((f16x4*)(out + (size_t)row * HDIM))[t] = o;
}

// ---------------- main NT GEMM: C[M,N] = A[M,K] @ BT[N,K]^T + bias ----------------
// 512 threads / 8 waves (2x4 grid, wave tile 64x32), 128x128 block tile, BK=64.
// Async staging: row = 64 f16 = 8 chunks of 16B; chunk rotation rot=row&7 puts
// ds_read_b128 fragment reads at the b128 bank floor (8 lanes / 4-bank group).
// EPI: 0 = relu->f16, 1 = f16, 2 = fp32, 3 = fp32 += existing, 4 = f16 no-bias
template <int EPI>
__global__ __launch_bounds__(512) void gemm_nt(
    const f16* __restrict__ A, const f16* __restrict__ BT,
    const float* __restrict__ bias, void* __restrict__ Cout, int N, int K) {
  __shared__ __align__(16) f16 As[128 * 64];
  __shared__ __align__(16) f16 Bs[128 * 64];
  const int tid = threadIdx.x;
  const int wave = tid >> 6, lane = tid & 63;
  const int l15 = lane & 15, quad = lane >> 4;

  // block swizzle: groups of up to 16 bm, bn inner
  const int gn = N >> 7;
  const int gm = (int)gridDim.x / gn;
  const int pid = blockIdx.x;
  const int npg = 16 * gn;
  const int gid = pid / npg;
  const int rem = pid - gid * npg;
  const int grows = min(16, gm - gid * 16);
  const int bm = gid * 16 + rem % grows;
  const int bn = rem / grows;

  const int wm = wave >> 2, wn = wave & 3;   // 2 x 4 wave grid; wave tile 64x32

  f32x4 z4 = {0.f, 0.f, 0.f, 0.f};
  f32x4 acc[4][2];
#pragma unroll
  for (int i = 0; i < 4; i++)
#pragma unroll
    for (int j = 0; j < 2; j++) acc[i][j] = z4;

  // staging: thread covers (row = tid>>3 in 0..63, phys chunk p = tid&7);
  // logical source chunk c = (p - rot)&7, rot(row) = row&7 = (tid>>3)&7.
  const int srow = tid >> 3;
  const int c = ((tid & 7) - (srow & 7)) & 7;
  const f16* Ag = A + (size_t)(bm * 128 + srow) * K + c * 8;
  const f16* Bg = BT + (size_t)(bn * 128 + srow) * K + c * 8;
  f16* Al0 = As + tid * 8;             // = row*64 + p*8
  f16* Al1 = As + 64 * 64 + tid * 8;   // rows 64..127
  f16* Bl0 = Bs + tid * 8;
  f16* Bl1 = Bs + 64 * 64 + tid * 8;
  const size_t kstep = (size_t)64 * K;

  const int r7 = l15 & 7;  // fragment-row rotation (row&7 = l15&7)

  for (int k0 = 0; k0 < K; k0 += 64) {
    async_copy16(Ag, Al0);
    async_copy16(Ag + kstep, Al1);
    async_copy16(Bg, Bl0);
    async_copy16(Bg + kstep, Bl1);
    Ag += 64; Bg += 64;
    __syncthreads();
#pragma unroll
    for (int s = 0; s < 2; s++) {
      f16x8 af[4], bfr[2];
#pragma unroll
      for (int t = 0; t < 4; t++) {
        int phys = (s * 4 + quad + r7) & 7;
        af[t] = *(const f16x8*)&As[(wm * 64 + t * 16 + l15) * 64 + phys * 8];
      }
#pragma unroll
      for (int u = 0; u < 2; u++) {
        int phys = (s * 4 + quad + r7) & 7;
        bfr[u] = *(const f16x8*)&Bs[(wn * 32 + u * 16 + l15) * 64 + phys * 8];
      }
#pragma unroll
      for (int i = 0; i < 4; i++)
#pragma unroll
        for (int j = 0; j < 2; j++)
          acc[i][j] = __builtin_amdgcn_mfma_f32_16x16x32_f16(af[i], bfr[j], acc[i][j], 0, 0, 0);
    }
    __syncthreads();
  }

  float* Cf = (float*)Cout;
  f16* Ch = (f16*)Cout;
#pragma unroll
  for (int i = 0; i < 4; i++) {
    int r0 = bm * 128 + wm * 64 + i * 16 + quad * 4;
#pragma unroll
    for (int j = 0; j < 2; j++) {
      int cc = bn * 128 + wn * 32 + j * 16 + l15;
      float bv = (EPI == 4) ? 0.f : bias[cc];
#pragma unroll
      for (int reg = 0; reg < 4; reg++) {
        size_t idx = (size_t)(r0 + reg) * N + cc;
        float v = acc[i][j][reg] + bv;
        if (EPI == 0)      Ch[idx] = (f16)fmaxf(v, 0.f);
        else if (EPI == 1) Ch[idx] = (f16)v;
        else if (EPI == 2) Cf[idx] = v;
        else if (EPI == 3) { float rv = Cf[idx]; Cf[idx] = v + rv; }
        else               Ch[idx] = (f16)v;
      }
    }
  }
}

// ---------------- flash attention with zeroed-diagonal scores ----------------
// grid: 2048 = qc(4) x h(8) x b(64). 256 thr / 4 waves; wave owns 32 q-rows.
// K/VT tiles staged via rotated global_load_lds (no register round-trip):
//   Ks row = 128 f16 = 16 chunks, rot = row&15; VTs row = 64 f16 = 8 chunks, rot = row&7.
// Fixed-max softmax (scores O(1): p=exp(s), diag->1). Ps wave-private (lgkm wait only).
__global__ __launch_bounds__(256) void attn_kernel(
    const f16* __restrict__ qkv, const f16* __restrict__ vT,
    f16* __restrict__ ctx) {
  const int tid = threadIdx.x;
  const int wave = tid >> 6, lane = tid & 63;
  const int l15 = lane & 15, quad = lane >> 4;
  const int bidx = blockIdx.x;
  const int qc = bidx & 3, h = (bidx >> 2) & 7, bb = bidx >> 5;

  const f16* Qbase = qkv + (size_t)(bb * SEQ) * QKV_LD + h * 128;
  const f16* Kbase = Qbase + 1024;
  const f16* VTbase = vT + (size_t)(bb * NHEAD + h) * HD * SEQ;

  __shared__ __align__(16) f16 Ks[64 * 128];    // rotated chunks, no pad
  __shared__ __align__(16) f16 VTs[128 * 64];   // rotated chunks, no pad
  __shared__ __align__(16) f16 Ps[4 * 32 * 72]; // per-wave 32 x [72] (64 used)

  const float scale = 0.08838834764831845f;  // 1/sqrt(128)
  const int qrow0 = qc * 128 + wave * 32;
  f16x8 qf[2][4];
#pragma unroll
  for (int tm = 0; tm < 2; tm++)
#pragma unroll
    for (int s = 0; s < 4; s++) {
      qf[tm][s] = *(const f16x8*)(Qbase + (size_t)(qrow0 + tm * 16 + l15) * QKV_LD + s * 32 + quad * 8);
#pragma unroll
      for (int e = 0; e < 8; e++) qf[tm][s][e] *= (f16)scale;  // fold 1/sqrt(HD) into Q
    }

  f32x4 z4 = {0.f, 0.f, 0.f, 0.f};
  f32x4 O[2][8];
#pragma unroll
  for (int i = 0; i < 2; i++)
#pragma unroll
    for (int j = 0; j < 8; j++) O[i][j] = z4;
  float lrow[2][4];
#pragma unroll
  for (int i = 0; i < 2; i++)
#pragma unroll
    for (int r = 0; r < 4; r++) lrow[i][r] = 0.f;

  // K staging: srow = tid>>4 (0..15), p = tid&15, c = (p - srow)&15
  const int ksrow = tid >> 4;
  const int kc = ((tid & 15) - ksrow) & 15;
  const f16* Kg = Kbase + (size_t)ksrow * QKV_LD + kc * 8;
  f16* Kl = Ks + tid * 8;            // row*128 + p*8 = 8*tid (per 16-row slab)
  // VT staging: srow = tid>>3 (0..31), p = tid&7, c = (p - (srow&7))&7
  const int vsrow = tid >> 3;
  const int vc = ((tid & 7) - (vsrow & 7)) & 7;
  const f16* Vg = VTbase + (size_t)vsrow * SEQ + vc * 8;
  f16* Vl = VTs + tid * 8;           // row*64 + p*8 = 8*tid (per 32-row slab)

  f16* Pw = &Ps[wave * 32 * 72];
  const int r7 = l15 & 7;

  for (int kt = 0; kt < 8; kt++) {
    const int krow0 = kt * 64;
#pragma unroll
    for (int i = 0; i < 4; i++)
      async_copy16(Kg + (size_t)(krow0 + 16 * i) * QKV_LD, Kl + 2048 * i);
#pragma unroll
    for (int i = 0; i < 4; i++)
      async_copy16(Vg + (size_t)(32 * i) * SEQ + krow0, Vl + 2048 * i);
    __syncthreads();

    // S = Q @ K^T   (2x4 tiles of 16x16, K-dim = HD = 128 -> 4 mfma steps)
    f32x4 S[2][4];
#pragma unroll
    for (int i = 0; i < 2; i++)
#pragma unroll
      for (int j = 0; j < 4; j++) S[i][j] = z4;
#pragma unroll
    for (int s = 0; s < 4; s++) {
      f16x8 bfr[4];
#pragma unroll
      for (int tn = 0; tn < 4; tn++) {
        int phys = (s * 4 + quad + l15) & 15;
        bfr[tn] = *(const f16x8*)&Ks[(tn * 16 + l15) * 128 + phys * 8];
      }
#pragma unroll
      for (int tm = 0; tm < 2; tm++)
#pragma unroll
        for (int tn = 0; tn < 4; tn++)
          S[tm][tn] = __builtin_amdgcn_mfma_f32_16x16x32_f16(qf[tm][s], bfr[tn], S[tm][tn], 0, 0, 0);
    }

    // fixed-max softmax (C-layout row = quad*4+reg; diag score -> exp(0)=1)
#pragma unroll
    for (int tm = 0; tm < 2; tm++) {
#pragma unroll
      for (int reg = 0; reg < 4; reg++) {
        int qg = qrow0 + tm * 16 + quad * 4 + reg;
        float rs = 0.f;
#pragma unroll
        for (int tn = 0; tn < 4; tn++) {
          int kg = krow0 + tn * 16 + l15;
          float p = (kg == qg) ? 1.f : __expf(S[tm][tn][reg]);
          S[tm][tn][reg] = p;
          rs += p;
        }
        rs += __shfl_xor(rs, 1); rs += __shfl_xor(rs, 2);
        rs += __shfl_xor(rs, 4); rs += __shfl_xor(rs, 8);
        lrow[tm][reg] += rs;
      }
    }

    // P: C-layout -> LDS (wave-private) -> A-layout
#pragma unroll
    for (int tm = 0; tm < 2; tm++)
#pragma unroll
      for (int reg = 0; reg < 4; reg++)
#pragma unroll
        for (int tn = 0; tn < 4; tn++)
          Pw[(tm * 16 + quad * 4 + reg) * 72 + tn * 16 + l15] = (f16)S[tm][tn][reg];
    asm volatile("s_waitcnt lgkmcnt(0)" ::: "memory");  // own-wave LDS writes visible

    // O += P @ V  (V as VT rows: NT gemm; K-dim = 64 -> 2 mfma steps)
#pragma unroll
    for (int ks = 0; ks < 2; ks++) {
      f16x8 pa[2];
#pragma unroll
      for (int tm = 0; tm < 2; tm++)
        pa[tm] = *(const f16x8*)&Pw[(tm * 16 + l15) * 72 + ks * 32 + quad * 8];
#pragma unroll
      for (int tn = 0; tn < 8; tn++) {
        int phys = (ks * 4 + quad + r7) & 7;
        f16x8 vb = *(const f16x8*)&VTs[(tn * 16 + l15) * 64 + phys * 8];
#pragma unroll
        for (int tm = 0; tm < 2; tm++)
          O[tm][tn] = __builtin_amdgcn_mfma_f32_16x16x32_f16(pa[tm], vb, O[tm][tn], 0, 0, 0);
      }
    }
    __syncthreads();
  }

  // epilogue: O / l -> ctx [B*M, H] (head-major cols)
#pragma unroll
  for (int tm = 0; tm < 2; tm++)
#pragma unroll
    for (int reg = 0; reg < 4; reg++) {
      float inv = 1.f / lrow[tm][reg];
      int row = bb * SEQ + qc * 128 + wave * 32 + tm * 16 + quad * 4 + reg;
#pragma unroll
      for (int tn = 0; tn < 8; tn++) {
        int col = h * 128 + tn * 16 + l15;
        ctx[(size_t)row * HDIM + col] = (f16)(O[tm][tn][reg] * inv);
      }
    }
}

// ---------------- launch ----------------

extern "C" void kernel_launch(void* const* d_in, const int* in_sizes, int n_in,
                              void* d_out, int out_size, void* d_ws, size_t ws_size,
                              hipStream_t stream) {
  (void)in_sizes; (void)n_in; (void)out_size; (void)ws_size;
  const float* x      = (const float*)d_in[0];
  const float* conv_w = (const float*)d_in[1];
  const float* conv_b = (const float*)d_in[2];
  const float* w1     = (const float*)d_in[3];
  const float* b1     = (const float*)d_in[4];
  const float* w2     = (const float*)d_in[5];
  const float* b2     = (const float*)d_in[6];
  const float* ln_g   = (const float*)d_in[7];
  const float* ln_b   = (const float*)d_in[8];
  const float* wq     = (const float*)d_in[9];
  const float* bq     = (const float*)d_in[10];
  const float* wk     = (const float*)d_in[11];
  const float* bk     = (const float*)d_in[12];
  const float* wv     = (const float*)d_in[13];
  const float* bv     = (const float*)d_in[14];
  const float* wo     = (const float*)d_in[15];
  const float* bo     = (const float*)d_in[16];
  const float* wp     = (const float*)d_in[17];
  const float* bp     = (const float*)d_in[18];
  float* out = (float*)d_out;

  char* ws = (char*)d_ws;
  size_t off = 0;
  auto alloc = [&](size_t bytes) {
    char* p = ws + off;
    off += (bytes + 255) & ~(size_t)255;
    return p;
  };
  float* cs   = (float*)alloc(8);
  f16* w1T    = (f16*)alloc((size_t)1024 * 512 * 2);
  f16* w2T    = (f16*)alloc((size_t)1024 * 1024 * 2);
  f16* qkvT   = (f16*)alloc((size_t)3072 * 1024 * 2);
  f16* wpT    = (f16*)alloc((size_t)1024 * 1024 * 2);
  f16* woh    = (f16*)alloc((size_t)1024 * 1024 * 2);  // wo cast f16 row-major
  f16* woPT   = (f16*)alloc((size_t)1024 * 1024 * 2);  // (wo@wp) in NT layout
  float* bqkv = (float*)alloc((size_t)3072 * 4);
  float* bp2  = (float*)alloc((size_t)1024 * 4);
  f16* qkv    = (f16*)alloc((size_t)MR * 3072 * 2);  // 192 MB; front reused as xh
  f16* h1     = (f16*)alloc((size_t)MR * 1024 * 2);  // 64 MB; reused as vT
  f16* x_norm = (f16*)alloc((size_t)MR * 1024 * 2);  // 64 MB; reused as ctx
  f16* xh = qkv;   // [32768,512] dead before qkv is written
  f16* vT = h1;    // h1 dead after gemm2
  f16* ctx = x_norm;  // x_norm dead after QKV gemm
  // x_reg (fp32) lives in d_out; final gemm adds residual in-place.

  dim3 tb(32, 8);
  conv_reduce<<<1, 256, 0, stream>>>(conv_w, conv_b, cs);
  transpose_cast<<<dim3(32, 16), tb, 0, stream>>>(w1, w1T, 512, 1024);
  transpose_cast<<<dim3(32, 32), tb, 0, stream>>>(w2, w2T, 1024, 1024);
  transpose_cast<<<dim3(32, 32), tb, 0, stream>>>(wq, qkvT, 1024, 1024);
  transpose_cast<<<dim3(32, 32), tb, 0, stream>>>(wk, qkvT + (size_t)1024 * 1024, 1024, 1024);
  transpose_cast<<<dim3(32, 32), tb, 0, stream>>>(wv, qkvT + (size_t)2048 * 1024, 1024, 1024);
  transpose_cast<<<dim3(32, 32), tb, 0, stream>>>(wp, wpT, 1024, 1024);
  cast_f16<<<1024, 256, 0, stream>>>(wo, woh);
  concat_bias<<<12, 256, 0, stream>>>(bq, bk, bv, bqkv);
  fuse_bias<<<4, 256, 0, stream>>>(bo, wp, bp, bp2);
  prep_x<<<16384, 256, 0, stream>>>(x, cs, xh);

  // woPT[n][k] = (wo@wp)[k][n]: C[m=n][n=k] = sum_j wpT[n][j] * woh[k][j]
  gemm_nt<4><<<dim3(64), 512, 0, stream>>>(wpT, woh, nullptr, (void*)woPT, 1024, 1024);

  gemm_nt<0><<<dim3(256 * 8),  512, 0, stream>>>(xh, w1T, b1, (void*)h1, 1024, 512);
  gemm_nt<2><<<dim3(256 * 8),  512, 0, stream>>>(h1, w2T, b2, (void*)out, 1024, 1024);   // x_reg -> d_out
  ln_kernel<<<32768, 256, 0, stream>>>(out, ln_g, ln_b, x_norm);
  gemm_nt<1><<<dim3(256 * 24), 512, 0, stream>>>(x_norm, qkvT, bqkv, (void*)qkv, 3072, 1024);
  transpose_v<<<dim3(16, 4, 512), tb, 0, stream>>>(qkv, vT);
  attn_kernel<<<2048, 256, 0, stream>>>(qkv, vT, ctx);
  // fused wo+wp: out = ctx @ woP + bp2 + x_reg (in-place residual)
  gemm_nt<3><<<dim3(256 * 8), 512, 0, stream>>>(ctx, woPT, bp2, (void*)out, 1024, 1024);
}

// Round 5
// 893.935 us; speedup vs baseline: 1.4814x; 1.2158x over previous
//
#include <hip/hip_runtime.h>
#include <hip/hip_fp16.h>
#include <cstdint>
#include <cstddef>

typedef _Float16 f16;
typedef _Float16 f16x8 __attribute__((ext_vector_type(8)));
typedef _Float16 f16x4 __attribute__((ext_vector_type(4)));
typedef float f32x4 __attribute__((ext_vector_type(4)));

#define NB 64
#define SEQ 512
#define HDIM 1024
#define NHEAD 8
#define HD 128
#define MR (NB * SEQ)      // 32768 rows
#define QK_LD 2048         // q,k packed rows (v goes straight to vT)

// async 16B/lane global->LDS. LDS dest = wave-uniform base + lane*16.
__device__ __forceinline__ void async_copy16(const f16* g, f16* l) {
  __builtin_amdgcn_global_load_lds(
      (__attribute__((address_space(1))) void*)(void*)const_cast<f16*>(g),
      (__attribute__((address_space(3))) void*)l, 16, 0, 0);
}

// ---------------- small prep kernels ----------------

__global__ __launch_bounds__(256) void conv_reduce(
    const float* __restrict__ cw, const float* __restrict__ cb,
    float* __restrict__ out2) {
  int t = threadIdx.x;
  float a = 0.f, b = 0.f;
  for (int i = t; i < HDIM; i += 256) { a += cw[i]; b += cb[i]; }
  for (int m = 32; m >= 1; m >>= 1) { a += __shfl_xor(a, m); b += __shfl_xor(b, m); }
  __shared__ float sa[4], sb[4];
  if ((t & 63) == 0) { sa[t >> 6] = a; sb[t >> 6] = b; }
  __syncthreads();
  if (t == 0) {
    out2[0] = (sa[0] + sa[1] + sa[2] + sa[3]) * (1.f / HDIM);
    out2[1] = (sb[0] + sb[1] + sb[2] + sb[3]) * (1.f / HDIM);
  }
}

// y = x*(1+mean(conv_w)) + mean(conv_b), cast f16. 4 elems/thread.
__global__ __launch_bounds__(256) void prep_x(
    const float* __restrict__ x, const float* __restrict__ cs,
    f16* __restrict__ xh) {
  size_t i = (size_t)blockIdx.x * 256 + threadIdx.x;
  float cw = 1.f + cs[0], cb = cs[1];
  float4 v = ((const float4*)x)[i];
  f16x4 o;
  o[0] = (f16)(v.x * cw + cb);
  o[1] = (f16)(v.y * cw + cb);
  o[2] = (f16)(v.z * cw + cb);
  o[3] = (f16)(v.w * cw + cb);
  ((f16x4*)xh)[i] = o;
}

__global__ __launch_bounds__(256) void concat_bias(
    const float* __restrict__ bq, const float* __restrict__ bk,
    const float* __restrict__ bv, float* __restrict__ dst) {
  int i = blockIdx.x * 256 + threadIdx.x;  // 3072
  if (i < 1024) dst[i] = bq[i];
  else if (i < 2048) dst[i] = bk[i - 1024];
  else dst[i] = bv[i - 2048];
}

// fp32 -> f16 elementwise (no transpose), 4 elems/thread
__global__ __launch_bounds__(256) void cast_f16(
    const float* __restrict__ src, f16* __restrict__ dst) {
  size_t i = (size_t)blockIdx.x * 256 + threadIdx.x;
  float4 v = ((const float4*)src)[i];
  f16x4 o;
  o[0] = (f16)v.x; o[1] = (f16)v.y; o[2] = (f16)v.z; o[3] = (f16)v.w;
  ((f16x4*)dst)[i] = o;
}

// phase1: partial[jc][n] = sum_{j in chunk jc} bo[j]*wp[j][n];  grid (4, 8)
__global__ __launch_bounds__(256) void fuse_bias_p1(
    const float* __restrict__ bo, const float* __restrict__ wp,
    float* __restrict__ partial) {
  int n = blockIdx.x * 256 + threadIdx.x;
  int jc = blockIdx.y;
  float s = 0.f;
#pragma unroll 8
  for (int j = jc * 128; j < jc * 128 + 128; j++) s += bo[j] * wp[(size_t)j * 1024 + n];
  partial[(size_t)jc * 1024 + n] = s;
}

// phase2: bp2[n] = bp[n] + sum_jc partial[jc][n];  grid 4
__global__ __launch_bounds__(256) void fuse_bias_p2(
    const float* __restrict__ partial, const float* __restrict__ bp,
    float* __restrict__ bp2) {
  int n = blockIdx.x * 256 + threadIdx.x;
  float s = bp[n];
#pragma unroll
  for (int jc = 0; jc < 8; jc++) s += partial[(size_t)jc * 1024 + n];
  bp2[n] = s;
}

// W [K,N] fp32 -> WT [N,K] f16 (NT-gemm weight layout)
__global__ __launch_bounds__(256) void transpose_cast(
    const float* __restrict__ src, f16* __restrict__ dst, int K, int N) {
  __shared__ float tile[32][33];
  int tx = threadIdx.x, ty = threadIdx.y;
  int n0 = blockIdx.x * 32, k0 = blockIdx.y * 32;
#pragma unroll
  for (int r = 0; r < 32; r += 8) tile[ty + r][tx] = src[(size_t)(k0 + ty + r) * N + n0 + tx];
  __syncthreads();
#pragma unroll
  for (int r = 0; r < 32; r += 8)
    dst[(size_t)(n0 + ty + r) * K + k0 + tx] = (f16)tile[tx][ty + r];
}

// five 1024x1024 transpose_casts in one launch; z selects (src,dst)
__global__ __launch_bounds__(256) void transpose_cast5(
    const float* s0, const float* s1, const float* s2, const float* s3, const float* s4,
    f16* d0, f16* d1, f16* d2, f16* d3, f16* d4) {
  const float* src; f16* dst;
  switch (blockIdx.z) {
    case 0: src = s0; dst = d0; break;
    case 1: src = s1; dst = d1; break;
    case 2: src = s2; dst = d2; break;
    case 3: src = s3; dst = d3; break;
    default: src = s4; dst = d4; break;
  }
  __shared__ float tile[32][33];
  int tx = threadIdx.x, ty = threadIdx.y;
  int n0 = blockIdx.x * 32, k0 = blockIdx.y * 32;
#pragma unroll
  for (int r = 0; r < 32; r += 8) tile[ty + r][tx] = src[(size_t)(k0 + ty + r) * 1024 + n0 + tx];
  __syncthreads();
#pragma unroll
  for (int r = 0; r < 32; r += 8)
    dst[(size_t)(n0 + ty + r) * 1024 + k0 + tx] = (f16)tile[tx][ty + r];
}

// LayerNorm over H=1024, f16 in (x_regh), f16 out (x_norm)
__global__ __launch_bounds__(256) void ln_kernel(
    const f16* __restrict__ xin, const float* __restrict__ g,
    const float* __restrict__ bta, f16* __restrict__ out) {
  int row = blockIdx.x;
  int t = threadIdx.x;
  f16x4 vh = ((const f16x4*)(xin + (size_t)row * HDIM))[t];
  float vx = (float)vh[0], vy = (float)vh[1], vz = (float)vh[2], vw = (float)vh[3];
  float s = vx + vy + vz + vw;
  float s2 = vx * vx + vy * vy + vz * vz + vw * vw;
  for (int m = 32; m >= 1; m >>= 1) { s += __shfl_xor(s, m); s2 += __shfl_xor(s2, m); }
  __shared__ float sa[4], sb[4];
  if ((t & 63) == 0) { sa[t >> 6] = s; sb[t >> 6] = s2; }
  __syncthreads();
  float S = sa[0] + sa[1] + sa[2] + sa[3];
  float S2 = sb[0] + sb[1] + sb[2] + sb[3];
  float mu = S * (1.f / HDIM);
  float var = S2 * (1.f / HDIM) - mu * mu;
  float inv = rsqrtf(var + 1e-5f);
  float4 gv = ((const float4*)g)[t];
  float4 bv = ((const float4*)bta)[t];
  f16x4 o;
  o[0] = (f16)((vx - mu) * inv * gv.x + bv.x);
  o[1] = (f16)((vy - mu) * inv * gv.y + bv.y);
  o[2] = (f16)((vz - mu) * inv * gv.z + bv.z);
  o[3] = (f16)((vw - mu) * inv * gv.w + bv.w);
  ((f16x4*)(out + (size_t)row * HDIM))[t] = o;
}

// ---------------- main NT GEMM: C[M,N] = A[M,K] @ BT[N,K]^T + bias ----------------
// 512 threads / 8 waves (2x4 grid, wave tile 64x32), 128x128 block tile, BK=64.
// Rotated global_load_lds staging (bank-floor b128 reads, R4-verified conflict-free).
// EPI: 0 relu->f16 | 1 f16 | 4 f16 no-bias | 5 fp32 = acc+bias+(float)Xres (residual)
//      6 QKV: cols<2048 -> f16 @ LD 2048; cols>=2048 -> V written to vT layout
template <int EPI>
__global__ __launch_bounds__(512) void gemm_nt(
    const f16* __restrict__ A, const f16* __restrict__ BT,
    const float* __restrict__ bias, void* __restrict__ Cout, int N, int K,
    const f16* __restrict__ Xres, f16* __restrict__ vTout) {
  __shared__ __align__(16) f16 As[128 * 64];
  __shared__ __align__(16) f16 Bs[128 * 64];
  const int tid = threadIdx.x;
  const int wave = tid >> 6, lane = tid & 63;
  const int l15 = lane & 15, quad = lane >> 4;

  // block swizzle: groups of up to 16 bm, bn inner
  const int gn = N >> 7;
  const int gm = (int)gridDim.x / gn;
  const int pid = blockIdx.x;
  const int npg = 16 * gn;
  const int gid = pid / npg;
  const int rem = pid - gid * npg;
  const int grows = min(16, gm - gid * 16);
  const int bm = gid * 16 + rem % grows;
  const int bn = rem / grows;

  const int wm = wave >> 2, wn = wave & 3;   // 2 x 4 wave grid; wave tile 64x32

  f32x4 z4 = {0.f, 0.f, 0.f, 0.f};
  f32x4 acc[4][2];
#pragma unroll
  for (int i = 0; i < 4; i++)
#pragma unroll
    for (int j = 0; j < 2; j++) acc[i][j] = z4;

  // staging: row = tid>>3 (0..63), phys chunk p = tid&7, logical c = (p - row&7)&7
  const int srow = tid >> 3;
  const int c = ((tid & 7) - (srow & 7)) & 7;
  const f16* Ag = A + (size_t)(bm * 128 + srow) * K + c * 8;
  const f16* Bg = BT + (size_t)(bn * 128 + srow) * K + c * 8;
  f16* Al0 = As + tid * 8;
  f16* Al1 = As + 64 * 64 + tid * 8;
  f16* Bl0 = Bs + tid * 8;
  f16* Bl1 = Bs + 64 * 64 + tid * 8;
  const size_t kstep = (size_t)64 * K;

  const int r7 = l15 & 7;  // fragment-row rotation

  for (int k0 = 0; k0 < K; k0 += 64) {
    async_copy16(Ag, Al0);
    async_copy16(Ag + kstep, Al1);
    async_copy16(Bg, Bl0);
    async_copy16(Bg + kstep, Bl1);
    Ag += 64; Bg += 64;
    __syncthreads();
#pragma unroll
    for (int s = 0; s < 2; s++) {
      f16x8 af[4], bfr[2];
#pragma unroll
      for (int t = 0; t < 4; t++) {
        int phys = (s * 4 + quad + r7) & 7;
        af[t] = *(const f16x8*)&As[(wm * 64 + t * 16 + l15) * 64 + phys * 8];
      }
#pragma unroll
      for (int u = 0; u < 2; u++) {
        int phys = (s * 4 + quad + r7) & 7;
        bfr[u] = *(const f16x8*)&Bs[(wn * 32 + u * 16 + l15) * 64 + phys * 8];
      }
#pragma unroll
      for (int i = 0; i < 4; i++)
#pragma unroll
        for (int j = 0; j < 2; j++)
          acc[i][j] = __builtin_amdgcn_mfma_f32_16x16x32_f16(af[i], bfr[j], acc[i][j], 0, 0, 0);
    }
    __syncthreads();
  }

  float* Cf = (float*)Cout;
  f16* Ch = (f16*)Cout;
#pragma unroll
  for (int i = 0; i < 4; i++) {
    int r0 = bm * 128 + wm * 64 + i * 16 + quad * 4;
#pragma unroll
    for (int j = 0; j < 2; j++) {
      int c0 = bn * 128 + wn * 32 + j * 16;
      int cc = c0 + l15;
      float bv = (EPI == 4) ? 0.f : bias[cc];
      if (EPI == 6 && c0 >= 2048) {
        // V part -> vT[(b*8+h)*128 + d][m], 4 consecutive m per lane
        int hh = (cc - 2048) >> 7, d = (cc - 2048) & 127;
        int bb = r0 >> 9, ml = r0 & 511;
        f16x4 o;
#pragma unroll
        for (int reg = 0; reg < 4; reg++) o[reg] = (f16)(acc[i][j][reg] + bv);
        *(f16x4*)&vTout[((size_t)(bb * NHEAD + hh) * HD + d) * SEQ + ml] = o;
      } else {
#pragma unroll
        for (int reg = 0; reg < 4; reg++) {
          float v = acc[i][j][reg] + bv;
          if (EPI == 0)      Ch[(size_t)(r0 + reg) * N + cc] = (f16)fmaxf(v, 0.f);
          else if (EPI == 1) Ch[(size_t)(r0 + reg) * N + cc] = (f16)v;
          else if (EPI == 4) Ch[(size_t)(r0 + reg) * N + cc] = (f16)v;
          else if (EPI == 5) {
            size_t idx = (size_t)(r0 + reg) * N + cc;
            Cf[idx] = v + (float)Xres[idx];
          } else {  // EPI == 6, q/k part, LD 2048
            Ch[(size_t)(r0 + reg) * QK_LD + cc] = (f16)v;
          }
        }
      }
    }
  }
}

// ---------------- flash attention with zeroed-diagonal scores ----------------
// grid: 1024 = bh(512) x qc(2).  512 thr / 8 waves; wave owns 32 q-rows (256/block).
// K/VT staged via rotated global_load_lds. Fixed-max softmax (p=exp(s), diag->1).
// Ps wave-private (lgkm wait only). LDS 69 KB -> 2 blocks/CU, 16 waves/CU.
__global__ __launch_bounds__(512) void attn_kernel(
    const f16* __restrict__ qkv, const f16* __restrict__ vT,
    f16* __restrict__ ctx) {
  const int tid = threadIdx.x;
  const int wave = tid >> 6, lane = tid & 63;
  const int l15 = lane & 15, quad = lane >> 4;
  const int bidx = blockIdx.x;
  const int qc = bidx >> 9;            // siblings 512 apart -> same XCD, co-resident
  const int bh = bidx & 511;
  const int h = bh & 7, bb = bh >> 3;

  const f16* Qbase = qkv + (size_t)(bb * SEQ) * QK_LD + h * 128;
  const f16* Kbase = Qbase + 1024;
  const f16* VTbase = vT + (size_t)(bb * NHEAD + h) * HD * SEQ;

  __shared__ __align__(16) f16 Ks[64 * 128];    // rotated chunks
  __shared__ __align__(16) f16 VTs[128 * 64];   // rotated chunks
  __shared__ __align__(16) f16 Ps[8 * 32 * 72]; // per-wave 32 x [72] (64 used)

  const float scale = 0.08838834764831845f;  // 1/sqrt(128)
  const int qrow0 = qc * 256 + wave * 32;
  f16x8 qf[2][4];
#pragma unroll
  for (int tm = 0; tm < 2; tm++)
#pragma unroll
    for (int s = 0; s < 4; s++) {
      qf[tm][s] = *(const f16x8*)(Qbase + (size_t)(qrow0 + tm * 16 + l15) * QK_LD + s * 32 + quad * 8);
#pragma unroll
      for (int e = 0; e < 8; e++) qf[tm][s][e] *= (f16)scale;
    }

  f32x4 z4 = {0.f, 0.f, 0.f, 0.f};
  f32x4 O[2][8];
#pragma unroll
  for (int i = 0; i < 2; i++)
#pragma unroll
    for (int j = 0; j < 8; j++) O[i][j] = z4;
  float lrow[2][4];
#pragma unroll
  for (int i = 0; i < 2; i++)
#pragma unroll
    for (int r = 0; r < 4; r++) lrow[i][r] = 0.f;

  // K staging: row = 32*i + (tid>>4), p = tid&15, c = (p - row&15)&15
  const int kc = ((tid & 15) - ((tid >> 4) & 15)) & 15;
  const f16* Kg = Kbase + (size_t)(tid >> 4) * QK_LD + kc * 8;
  f16* Kl = Ks + tid * 8;
  // VT staging: row = 64*i + (tid>>3), p = tid&7, c = (p - row&7)&7
  const int vc = ((tid & 7) - ((tid >> 3) & 7)) & 7;
  const f16* Vg = VTbase + (size_t)(tid >> 3) * SEQ + vc * 8;
  f16* Vl = VTs + tid * 8;

  f16* Pw = &Ps[wave * 32 * 72];
  const int r7 = l15 & 7;

  for (int kt = 0; kt < 8; kt++) {
    const int krow0 = kt * 64;
#pragma unroll
    for (int i = 0; i < 2; i++)
      async_copy16(Kg + (size_t)(krow0 + 32 * i) * QK_LD, Kl + 4096 * i);
#pragma unroll
    for (int i = 0; i < 2; i++)
      async_copy16(Vg + (size_t)(64 * i) * SEQ + krow0, Vl + 4096 * i);
    __syncthreads();

    // S = Q @ K^T
    f32x4 S[2][4];
#pragma unroll
    for (int i = 0; i < 2; i++)
#pragma unroll
      for (int j = 0; j < 4; j++) S[i][j] = z4;
#pragma unroll
    for (int s = 0; s < 4; s++) {
      f16x8 bfr[4];
#pragma unroll
      for (int tn = 0; tn < 4; tn++) {
        int phys = (s * 4 + quad + l15) & 15;
        bfr[tn] = *(const f16x8*)&Ks[(tn * 16 + l15) * 128 + phys * 8];
      }
#pragma unroll
      for (int tm = 0; tm < 2; tm++)
#pragma unroll
        for (int tn = 0; tn < 4; tn++)
          S[tm][tn] = __builtin_amdgcn_mfma_f32_16x16x32_f16(qf[tm][s], bfr[tn], S[tm][tn], 0, 0, 0);
    }

    // fixed-max softmax (diag -> exp(0)=1)
#pragma unroll
    for (int tm = 0; tm < 2; tm++) {
#pragma unroll
      for (int reg = 0; reg < 4; reg++) {
        int qg = qrow0 + tm * 16 + quad * 4 + reg;
        float rs = 0.f;
#pragma unroll
        for (int tn = 0; tn < 4; tn++) {
          int kg = krow0 + tn * 16 + l15;
          float p = (kg == qg) ? 1.f : __expf(S[tm][tn][reg]);
          S[tm][tn][reg] = p;
          rs += p;
        }
        rs += __shfl_xor(rs, 1); rs += __shfl_xor(rs, 2);
        rs += __shfl_xor(rs, 4); rs += __shfl_xor(rs, 8);
        lrow[tm][reg] += rs;
      }
    }

    // P: C-layout -> LDS (wave-private) -> A-layout
#pragma unroll
    for (int tm = 0; tm < 2; tm++)
#pragma unroll
      for (int reg = 0; reg < 4; reg++)
#pragma unroll
        for (int tn = 0; tn < 4; tn++)
          Pw[(tm * 16 + quad * 4 + reg) * 72 + tn * 16 + l15] = (f16)S[tm][tn][reg];
    asm volatile("s_waitcnt lgkmcnt(0)" ::: "memory");

    // O += P @ V
#pragma unroll
    for (int ks = 0; ks < 2; ks++) {
      f16x8 pa[2];
#pragma unroll
      for (int tm = 0; tm < 2; tm++)
        pa[tm] = *(const f16x8*)&Pw[(tm * 16 + l15) * 72 + ks * 32 + quad * 8];
#pragma unroll
      for (int tn = 0; tn < 8; tn++) {
        int phys = (ks * 4 + quad + r7) & 7;
        f16x8 vb = *(const f16x8*)&VTs[(tn * 16 + l15) * 64 + phys * 8];
#pragma unroll
        for (int tm = 0; tm < 2; tm++)
          O[tm][tn] = __builtin_amdgcn_mfma_f32_16x16x32_f16(pa[tm], vb, O[tm][tn], 0, 0, 0);
      }
    }
    __syncthreads();
  }

  // epilogue: O / l -> ctx [B*M, H]
#pragma unroll
  for (int tm = 0; tm < 2; tm++)
#pragma unroll
    for (int reg = 0; reg < 4; reg++) {
      float inv = 1.f / lrow[tm][reg];
      int row = bb * SEQ + qrow0 + tm * 16 + quad * 4 + reg;
#pragma unroll
      for (int tn = 0; tn < 8; tn++) {
        int col = h * 128 + tn * 16 + l15;
        ctx[(size_t)row * HDIM + col] = (f16)(O[tm][tn][reg] * inv);
      }
    }
}

// ---------------- launch ----------------

extern "C" void kernel_launch(void* const* d_in, const int* in_sizes, int n_in,
                              void* d_out, int out_size, void* d_ws, size_t ws_size,
                              hipStream_t stream) {
  (void)in_sizes; (void)n_in; (void)out_size; (void)ws_size;
  const float* x      = (const float*)d_in[0];
  const float* conv_w = (const float*)d_in[1];
  const float* conv_b = (const float*)d_in[2];
  const float* w1     = (const float*)d_in[3];
  const float* b1     = (const float*)d_in[4];
  const float* w2     = (const float*)d_in[5];
  const float* b2     = (const float*)d_in[6];
  const float* ln_g   = (const float*)d_in[7];
  const float* ln_b   = (const float*)d_in[8];
  const float* wq     = (const float*)d_in[9];
  const float* bq     = (const float*)d_in[10];
  const float* wk     = (const float*)d_in[11];
  const float* bk     = (const float*)d_in[12];
  const float* wv     = (const float*)d_in[13];
  const float* bv     = (const float*)d_in[14];
  const float* wo     = (const float*)d_in[15];
  const float* bo     = (const float*)d_in[16];
  const float* wp     = (const float*)d_in[17];
  const float* bp     = (const float*)d_in[18];
  float* out = (float*)d_out;

  char* ws = (char*)d_ws;
  size_t off = 0;
  auto alloc = [&](size_t bytes) {
    char* p = ws + off;
    off += (bytes + 255) & ~(size_t)255;
    return p;
  };
  float* cs    = (float*)alloc(8);
  f16* w1T     = (f16*)alloc((size_t)1024 * 512 * 2);
  f16* w2T     = (f16*)alloc((size_t)1024 * 1024 * 2);
  f16* qkvT    = (f16*)alloc((size_t)3072 * 1024 * 2);
  f16* wpT     = (f16*)alloc((size_t)1024 * 1024 * 2);
  f16* woh     = (f16*)alloc((size_t)1024 * 1024 * 2);
  f16* woPT    = (f16*)alloc((size_t)1024 * 1024 * 2);
  float* bqkv  = (float*)alloc((size_t)3072 * 4);
  float* bp2   = (float*)alloc((size_t)1024 * 4);
  float* part  = (float*)alloc((size_t)8 * 1024 * 4);
  f16* qkvQK   = (f16*)alloc((size_t)MR * QK_LD * 2);  // 128 MB; front reused as xh
  f16* h1      = (f16*)alloc((size_t)MR * 1024 * 2);   // 64 MB; reused as vT
  f16* x_norm  = (f16*)alloc((size_t)MR * 1024 * 2);   // 64 MB; reused as ctx
  f16* x_regh  = (f16*)alloc((size_t)MR * 1024 * 2);   // 64 MB (residual + LN input)
  f16* xh = qkvQK;    // [32768,512] dead before qkvQK written
  f16* vT = h1;       // h1 dead after w2 gemm
  f16* ctx = x_norm;  // x_norm dead after QKV gemm

  dim3 tb(32, 8);
  conv_reduce<<<1, 256, 0, stream>>>(conv_w, conv_b, cs);
  transpose_cast<<<dim3(32, 16), tb, 0, stream>>>(w1, w1T, 512, 1024);
  transpose_cast5<<<dim3(32, 32, 5), tb, 0, stream>>>(
      w2, wq, wk, wv, wp,
      w2T, qkvT, qkvT + (size_t)1024 * 1024, qkvT + (size_t)2048 * 1024, wpT);
  cast_f16<<<1024, 256, 0, stream>>>(wo, woh);
  concat_bias<<<12, 256, 0, stream>>>(bq, bk, bv, bqkv);
  fuse_bias_p1<<<dim3(4, 8), 256, 0, stream>>>(bo, wp, part);
  fuse_bias_p2<<<4, 256, 0, stream>>>(part, bp, bp2);
  prep_x<<<16384, 256, 0, stream>>>(x, cs, xh);

  // woPT[n][k] = (wo@wp)[k][n]
  gemm_nt<4><<<dim3(64), 512, 0, stream>>>(wpT, woh, nullptr, (void*)woPT, 1024, 1024, nullptr, nullptr);

  gemm_nt<0><<<dim3(256 * 8), 512, 0, stream>>>(xh, w1T, b1, (void*)h1, 1024, 512, nullptr, nullptr);
  gemm_nt<1><<<dim3(256 * 8), 512, 0, stream>>>(h1, w2T, b2, (void*)x_regh, 1024, 1024, nullptr, nullptr);
  ln_kernel<<<32768, 256, 0, stream>>>(x_regh, ln_g, ln_b, x_norm);
  // QKV: q,k -> qkvQK (LD 2048); v -> vT directly
  gemm_nt<6><<<dim3(256 * 24), 512, 0, stream>>>(x_norm, qkvT, bqkv, (void*)qkvQK, 3072, 1024, nullptr, vT);
  attn_kernel<<<1024, 512, 0, stream>>>(qkvQK, vT, ctx);
  // fused wo+wp: out = ctx @ woP + bp2 + x_reg
  gemm_nt<5><<<dim3(256 * 8), 512, 0, stream>>>(ctx, woPT, bp2, (void*)out, 1024, 1024, x_regh, nullptr);
}